// Round 11
// baseline (704.678 us; speedup 1.0000x reference)
//
#include <hip/hip_runtime.h>
#include <math.h>

#define H 128
#define STC 152   // LDS stride (shorts) for bf16 A-tiles
#define SOT 136   // LDS stride (shorts) for staged bf16 output tiles
#define SPQ 136   // LDS stride (shorts) for bf16 Spq (fallback classifier)
#define Z2S 69    // LDS stride (floats) for z2

typedef __attribute__((ext_vector_type(8))) short short8;
typedef __attribute__((ext_vector_type(4))) float f32x4;

__device__ inline unsigned short f2bf(float f) {
    unsigned int u = __float_as_uint(f);
    return (unsigned short)((u + 0x7fffu + ((u >> 16) & 1u)) >> 16);
}
__device__ inline float bflo(unsigned int v) { return __uint_as_float(v << 16); }
__device__ inline float bfhi(unsigned int v) { return __uint_as_float(v & 0xffff0000u); }
__device__ inline float bf2f(unsigned short v) { return __uint_as_float(((unsigned int)v) << 16); }

__device__ inline void fma4(float4& acc, float a, const float4 w) {
    acc.x = fmaf(a, w.x, acc.x);
    acc.y = fmaf(a, w.y, acc.y);
    acc.z = fmaf(a, w.z, acc.z);
    acc.w = fmaf(a, w.w, acc.w);
}

// ---------------- graph build ----------------

__global__ void count_kernel(const int* __restrict__ col, int E, int* __restrict__ cnt) {
    int e = blockIdx.x * blockDim.x + threadIdx.x;
    if (e < E) atomicAdd(&cnt[col[e]], 1);
}

__global__ void scan_sum_kernel(const int* __restrict__ cnt, int N, int* __restrict__ bsum) {
    int b = blockIdx.x, t = threadIdx.x;
    int base = b * 1024 + t * 4;
    int s = 0;
#pragma unroll
    for (int g = 0; g < 4; ++g) {
        int i = base + g;
        if (i < N) s += cnt[i];
    }
    for (int off = 32; off >= 1; off >>= 1) s += __shfl_down(s, off, 64);
    __shared__ int ws[4];
    if ((t & 63) == 0) ws[t >> 6] = s;
    __syncthreads();
    if (t == 0) bsum[b] = ws[0] + ws[1] + ws[2] + ws[3];
}

__global__ void scan_offsets_kernel(const int* __restrict__ bsum, int nb,
                                    int* __restrict__ boff, int* __restrict__ col_start, int N) {
    int lane = threadIdx.x;
    int v = (lane < nb) ? bsum[lane] : 0;
    int incl = v;
    for (int off = 1; off < 64; off <<= 1) {
        int u = __shfl_up(incl, off, 64);
        if (lane >= off) incl += u;
    }
    if (lane < nb) boff[lane] = incl - v;
    if (lane == 63) col_start[N] = incl;
}

__global__ void scan_write_kernel(const int* __restrict__ cnt, int N, const int* __restrict__ boff,
                                  int* __restrict__ col_start, int* __restrict__ cursor,
                                  float* __restrict__ dinv) {
    int b = blockIdx.x, t = threadIdx.x;
    int lane = t & 63, wv = t >> 6;
    int base = b * 1024 + t * 4;
    int c[4];
    int s = 0;
#pragma unroll
    for (int g = 0; g < 4; ++g) {
        int i = base + g;
        c[g] = (i < N) ? cnt[i] : 0;
        s += c[g];
    }
    int incl = s;
    for (int off = 1; off < 64; off <<= 1) {
        int u = __shfl_up(incl, off, 64);
        if (lane >= off) incl += u;
    }
    __shared__ int ws[4];
    if (lane == 63) ws[wv] = incl;
    __syncthreads();
    int run = boff[b] + incl - s;
    for (int w = 0; w < wv; ++w) run += ws[w];
#pragma unroll
    for (int g = 0; g < 4; ++g) {
        int i = base + g;
        if (i < N) {
            col_start[i] = run;
            cursor[i] = run;
            dinv[i] = rsqrtf((float)(c[g] + 1));
            run += c[g];
        }
    }
}

// CSC build; also records pos[e] = CSC position of edge e (inverse permutation)
__global__ void scatter_kernel(const int* __restrict__ row, const int* __restrict__ col, int E,
                               int* __restrict__ cursor, int* __restrict__ csc_src,
                               int2* __restrict__ csc_ec, int* __restrict__ csc_pos) {
    int e = blockIdx.x * blockDim.x + threadIdx.x;
    if (e < E) {
        int c = col[e];
        int p = atomicAdd(&cursor[c], 1);
        csc_src[p] = row[e];
        csc_ec[p] = make_int2(e, c);
        csc_pos[e] = p;
    }
}

// ---------------- GCN: aggregate-then-transform (bf16 dinv-prescaled features) ----------------

__global__ void aggx_kernel(const float* __restrict__ x, const int* __restrict__ col_start,
                            const int* __restrict__ csc_src, const float* __restrict__ dinv,
                            float* __restrict__ aggx, int N) {
    int t = blockIdx.x * blockDim.x + threadIdx.x;
    int i = t >> 3, f = t & 7;
    if (i >= N) return;
    int s0 = col_start[i], s1 = col_start[i + 1];
    float acc = 0.f;
    for (int p = s0; p < s1; ++p) {
        int s = csc_src[p];
        acc = fmaf(dinv[s], x[s * 8 + f], acc);
    }
    float di = dinv[i];
    aggx[i * 8 + f] = fmaf(di, acc, di * di * x[i * 8 + f]);
}

__global__ void xform8bf_kernel(const float* __restrict__ aggx, const float* __restrict__ W,
                                const float* __restrict__ b, const float* __restrict__ dinv,
                                unsigned int* __restrict__ out, int N) {
    int t = blockIdx.x * 256 + threadIdx.x;
    int i = t >> 6, jp = t & 63;
    if (i >= N) return;
    const float* ar = aggx + i * 8;
    float sc = dinv[i];
    int j0 = jp * 2;
    float a0 = b[j0], a1 = b[j0 + 1];
#pragma unroll
    for (int k = 0; k < 8; ++k) {
        float av = ar[k];
        a0 = fmaf(av, W[k * 128 + j0], a0);
        a1 = fmaf(av, W[k * 128 + j0 + 1], a1);
    }
    out[(size_t)i * 64 + jp] = (unsigned int)f2bf(sc * fmaxf(a0, 0.f)) |
                               ((unsigned int)f2bf(sc * fmaxf(a1, 0.f)) << 16);
}

__global__ __launch_bounds__(256) void agg128bf_kernel(
    const unsigned int* __restrict__ hd, const int* __restrict__ col_start,
    const int* __restrict__ csc_src, const float* __restrict__ dinv,
    unsigned int* __restrict__ out, int N) {
    int wv = threadIdx.x >> 6, lane = threadIdx.x & 63;
    int i = blockIdx.x * 4 + wv;
    if (i >= N) return;
    int s0 = col_start[i], s1 = col_start[i + 1];
    float ax = 0.f, ay = 0.f;
    int p = s0;
    for (; p + 8 <= s1; p += 8) {
        unsigned int v0 = hd[(size_t)csc_src[p + 0] * 64 + lane];
        unsigned int v1 = hd[(size_t)csc_src[p + 1] * 64 + lane];
        unsigned int v2 = hd[(size_t)csc_src[p + 2] * 64 + lane];
        unsigned int v3 = hd[(size_t)csc_src[p + 3] * 64 + lane];
        unsigned int v4 = hd[(size_t)csc_src[p + 4] * 64 + lane];
        unsigned int v5 = hd[(size_t)csc_src[p + 5] * 64 + lane];
        unsigned int v6 = hd[(size_t)csc_src[p + 6] * 64 + lane];
        unsigned int v7 = hd[(size_t)csc_src[p + 7] * 64 + lane];
        ax += bflo(v0) + bflo(v1) + bflo(v2) + bflo(v3) + bflo(v4) + bflo(v5) + bflo(v6) + bflo(v7);
        ay += bfhi(v0) + bfhi(v1) + bfhi(v2) + bfhi(v3) + bfhi(v4) + bfhi(v5) + bfhi(v6) + bfhi(v7);
    }
    for (; p < s1; ++p) {
        unsigned int v = hd[(size_t)csc_src[p] * 64 + lane];
        ax += bflo(v); ay += bfhi(v);
    }
    float di = dinv[i];
    unsigned int vs = hd[(size_t)i * 64 + lane];
    float rx = di * (ax + bflo(vs));
    float ry = di * (ay + bfhi(vs));
    out[(size_t)i * 64 + lane] = (unsigned int)f2bf(rx) | ((unsigned int)f2bf(ry) << 16);
}

__global__ __launch_bounds__(256) void xform_mfma_kernel(
    const unsigned short* __restrict__ in, const unsigned short* __restrict__ Bp,
    const float* __restrict__ b, const float* __restrict__ scale,
    unsigned short* __restrict__ out, int N) {
    __shared__ __align__(16) unsigned short sm[64 * STC];
    int tid = threadIdx.x;
    int i0 = blockIdx.x * 64;
    for (int u = tid; u < 1024; u += 256) {
        int i = u >> 4, l = u & 15;
        int node = i0 + i; if (node >= N) node = N - 1;
        uint4 v = ((const uint4*)in)[(size_t)node * 16 + l];
        *(uint4*)&sm[i * STC + l * 8] = v;
    }
    __syncthreads();
    int lane = tid & 63, w = tid >> 6, lm = lane & 15, quad = lane >> 4;
    int nt0 = 2 * w, nt1 = 2 * w + 1;
    f32x4 acc0[4], acc1[4];
    {
        float bv0 = b[nt0 * 16 + lm], bv1 = b[nt1 * 16 + lm];
        for (int m = 0; m < 4; ++m)
            for (int r = 0; r < 4; ++r) { acc0[m][r] = bv0; acc1[m][r] = bv1; }
    }
#pragma unroll
    for (int s = 0; s < 4; ++s) {
        short8 b0 = *(const short8*)&Bp[((size_t)(s * 8 + nt0) * 64 + lane) * 8];
        short8 b1 = *(const short8*)&Bp[((size_t)(s * 8 + nt1) * 64 + lane) * 8];
#pragma unroll
        for (int m = 0; m < 4; ++m) {
            short8 afr = *(const short8*)&sm[(m * 16 + lm) * STC + s * 32 + quad * 8];
            acc0[m] = __builtin_amdgcn_mfma_f32_16x16x32_bf16(afr, b0, acc0[m], 0, 0, 0);
            acc1[m] = __builtin_amdgcn_mfma_f32_16x16x32_bf16(afr, b1, acc1[m], 0, 0, 0);
        }
    }
    __syncthreads();
    for (int m = 0; m < 4; ++m)
        for (int r = 0; r < 4; ++r) {
            int rw = m * 16 + quad * 4 + r;
            int node = i0 + rw; if (node >= N) node = N - 1;
            float sc = scale ? scale[node] : 1.f;
            sm[rw * SOT + nt0 * 16 + lm] = f2bf(sc * fmaxf(acc0[m][r], 0.f));
            sm[rw * SOT + nt1 * 16 + lm] = f2bf(sc * fmaxf(acc1[m][r], 0.f));
        }
    __syncthreads();
    for (int u = tid; u < 1024; u += 256) {
        int i = u >> 4, l = u & 15;
        int node = i0 + i;
        if (node < N)
            *(uint4*)&out[(size_t)node * 128 + l * 8] = *(uint4*)&sm[i * SOT + l * 8];
    }
}

// ---------------- classifier weight prep ----------------

__global__ void weff_kernel(const float* __restrict__ We2, const float* __restrict__ Wc1,
                            float* __restrict__ Weff) {
    int idx = blockIdx.x * blockDim.x + threadIdx.x;
    int k = idx >> 7, c = idx & 127;
    float acc = 0.f;
    for (int j = 0; j < 128; ++j)
        acc = fmaf(We2[k * 128 + j], Wc1[(256 + j) * 128 + c], acc);
    Weff[idx] = acc;
}

__global__ void bc1p_kernel(const float* __restrict__ bc1, const float* __restrict__ be2,
                            const float* __restrict__ Wc1, float* __restrict__ bc1p) {
    int c = threadIdx.x;
    float acc = bc1[c];
    for (int j = 0; j < 128; ++j)
        acc = fmaf(be2[j], Wc1[(256 + j) * 128 + c], acc);
    bc1p[c] = acc;
}

__global__ void packg_kernel(const float* __restrict__ src, unsigned short* __restrict__ dst) {
    int idx = blockIdx.x * 256 + threadIdx.x;  // 2048
    int s = idx >> 9, nt = (idx >> 6) & 7, lane = idx & 63;
    int quad = lane >> 4, lm = lane & 15;
    int n = nt * 16 + lm, k0 = s * 32 + quad * 8;
    unsigned int p[4];
#pragma unroll
    for (int g = 0; g < 4; ++g) {
        p[g] = (unsigned int)f2bf(src[(k0 + 2 * g) * 128 + n]) |
               ((unsigned int)f2bf(src[(k0 + 2 * g + 1) * 128 + n]) << 16);
    }
    *(uint4*)&dst[(size_t)idx * 8] = make_uint4(p[0], p[1], p[2], p[3]);
}

__global__ void pack2_kernel(const float* __restrict__ Wc2, unsigned short* __restrict__ Bp2) {
    int idx = blockIdx.x * 256 + threadIdx.x;  // 1024
    int s = idx >> 8, nt = (idx >> 6) & 3, lane = idx & 63;
    int quad = lane >> 4, lm = lane & 15;
    int n = nt * 16 + lm, k0 = s * 32 + quad * 8;
    unsigned int p[4];
#pragma unroll
    for (int g = 0; g < 4; ++g) {
        p[g] = (unsigned int)f2bf(Wc2[(k0 + 2 * g) * 64 + n]) |
               ((unsigned int)f2bf(Wc2[(k0 + 2 * g + 1) * 64 + n]) << 16);
    }
    *(uint4*)&Bp2[(size_t)idx * 8] = make_uint4(p[0], p[1], p[2], p[3]);
}

// ---------------- fused h3 transform + P/Q precompute ----------------

__global__ __launch_bounds__(256) void h3pq_kernel(
    const unsigned short* __restrict__ in, const unsigned short* __restrict__ BpW3,
    const float* __restrict__ b3,
    const unsigned short* __restrict__ BpA, const unsigned short* __restrict__ BpB,
    const float* __restrict__ bc1p,
    unsigned short* __restrict__ P, unsigned short* __restrict__ Q, int N) {
    __shared__ __align__(16) unsigned short At[64 * STC];
    __shared__ __align__(16) unsigned short Hs[64 * SOT];
    int tid = threadIdx.x;
    int i0 = blockIdx.x * 64;
    for (int u = tid; u < 1024; u += 256) {
        int i = u >> 4, l = u & 15;
        int node = i0 + i; if (node >= N) node = N - 1;
        uint4 v = ((const uint4*)in)[(size_t)node * 16 + l];
        *(uint4*)&At[i * STC + l * 8] = v;
    }
    __syncthreads();
    int lane = tid & 63, w = tid >> 6, lm = lane & 15, quad = lane >> 4;

    {
        int nt0 = 2 * w, nt1 = 2 * w + 1;
        f32x4 a0[4], a1[4];
        float bv0 = b3[nt0 * 16 + lm], bv1 = b3[nt1 * 16 + lm];
        for (int m = 0; m < 4; ++m)
            for (int r = 0; r < 4; ++r) { a0[m][r] = bv0; a1[m][r] = bv1; }
#pragma unroll
        for (int s = 0; s < 4; ++s) {
            short8 b0 = *(const short8*)&BpW3[((size_t)(s * 8 + nt0) * 64 + lane) * 8];
            short8 b1 = *(const short8*)&BpW3[((size_t)(s * 8 + nt1) * 64 + lane) * 8];
#pragma unroll
            for (int m = 0; m < 4; ++m) {
                short8 afr = *(const short8*)&At[(m * 16 + lm) * STC + s * 32 + quad * 8];
                a0[m] = __builtin_amdgcn_mfma_f32_16x16x32_bf16(afr, b0, a0[m], 0, 0, 0);
                a1[m] = __builtin_amdgcn_mfma_f32_16x16x32_bf16(afr, b1, a1[m], 0, 0, 0);
            }
        }
        __syncthreads();
        for (int m = 0; m < 4; ++m)
            for (int r = 0; r < 4; ++r) {
                int rw = m * 16 + quad * 4 + r;
                Hs[rw * SOT + nt0 * 16 + lm] = f2bf(fmaxf(a0[m][r], 0.f));
                Hs[rw * SOT + nt1 * 16 + lm] = f2bf(fmaxf(a1[m][r], 0.f));
            }
    }
    __syncthreads();

    int half = w & 1;
    const unsigned short* Bp = (w >> 1) ? BpB : BpA;
    f32x4 acc[4][4];
    for (int nt = 0; nt < 4; ++nt) {
        float bv = (w >> 1) ? 0.f : bc1p[half * 64 + nt * 16 + lm];
        for (int m = 0; m < 4; ++m)
            for (int r = 0; r < 4; ++r) acc[nt][m][r] = bv;
    }
#pragma unroll
    for (int s = 0; s < 4; ++s) {
        short8 afr[4];
#pragma unroll
        for (int m = 0; m < 4; ++m)
            afr[m] = *(const short8*)&Hs[(m * 16 + lm) * SOT + s * 32 + quad * 8];
#pragma unroll
        for (int nt = 0; nt < 4; ++nt) {
            short8 bfr = *(const short8*)&Bp[((size_t)(s * 8 + half * 4 + nt) * 64 + lane) * 8];
#pragma unroll
            for (int m = 0; m < 4; ++m)
                acc[nt][m] = __builtin_amdgcn_mfma_f32_16x16x32_bf16(afr[m], bfr, acc[nt][m], 0, 0, 0);
        }
    }
    __syncthreads();
    unsigned short* St = At;

    if (w < 2) {
        for (int nt = 0; nt < 4; ++nt)
            for (int m = 0; m < 4; ++m)
                for (int r = 0; r < 4; ++r) {
                    int rw = m * 16 + quad * 4 + r;
                    St[rw * SOT + half * 64 + nt * 16 + lm] = f2bf(acc[nt][m][r]);
                }
    }
    __syncthreads();
    for (int u = tid; u < 1024; u += 256) {
        int i = u >> 4, l = u & 15;
        int node = i0 + i;
        if (node < N)
            *(uint4*)&P[(size_t)node * 128 + l * 8] = *(uint4*)&St[i * SOT + l * 8];
    }
    __syncthreads();
    if (w >= 2) {
        for (int nt = 0; nt < 4; ++nt)
            for (int m = 0; m < 4; ++m)
                for (int r = 0; r < 4; ++r) {
                    int rw = m * 16 + quad * 4 + r;
                    St[rw * SOT + half * 64 + nt * 16 + lm] = f2bf(acc[nt][m][r]);
                }
    }
    __syncthreads();
    for (int u = tid; u < 1024; u += 256) {
        int i = u >> 4, l = u & 15;
        int node = i0 + i;
        if (node < N)
            *(uint4*)&Q[(size_t)node * 128 + l * 8] = *(uint4*)&St[i * SOT + l * 8];
    }
}

// ---------------- U precompute v2: EDGE-order streaming reads, scatter writes ----------------

__global__ __launch_bounds__(256) void ucompute2_kernel(
    const int* __restrict__ csc_pos, const float* __restrict__ ea,
    const float* __restrict__ We1, const float* __restrict__ be1,
    const unsigned short* __restrict__ BpU, unsigned short* __restrict__ Um, int E) {
    __shared__ __align__(16) unsigned short At[64 * STC];  // t tile; overlay U staging [64][SOT]
    __shared__ int posS[64];
    int tid = threadIdx.x;
    int lane = tid & 63, w = tid >> 6, lm = lane & 15, quad = lane >> 4;

    short8 b0s[4], b1s[4];
#pragma unroll
    for (int s = 0; s < 4; ++s) {
        b0s[s] = *(const short8*)&BpU[((size_t)(s * 8 + 2 * w) * 64 + lane) * 8];
        b1s[s] = *(const short8*)&BpU[((size_t)(s * 8 + 2 * w + 1) * 64 + lane) * 8];
    }

    for (int t = 0; t < 4; ++t) {
        int e0 = (blockIdx.x * 4 + t) * 64;
        if (e0 >= E) break;
        if (tid < 64) {
            int e = e0 + tid;
            posS[tid] = (e < E) ? csc_pos[e] : 0;
        }
        {
            int i = tid >> 2, jv0 = (tid & 3) * 32;
            int e = e0 + i; if (e >= E) e = E - 1;
            float4 a = ((const float4*)ea)[e];
            const float4* W14 = (const float4*)We1;
            const float4* b14 = (const float4*)be1;
            for (int g = 0; g < 4; ++g) {
                int j0 = jv0 + g * 8, q = j0 >> 2;
                float4 r0 = b14[q], r1 = b14[q + 1];
                fma4(r0, a.x, W14[q]);      fma4(r1, a.x, W14[q + 1]);
                fma4(r0, a.y, W14[32 + q]); fma4(r1, a.y, W14[32 + q + 1]);
                fma4(r0, a.z, W14[64 + q]); fma4(r1, a.z, W14[64 + q + 1]);
                fma4(r0, a.w, W14[96 + q]); fma4(r1, a.w, W14[96 + q + 1]);
                unsigned int p0_ = (unsigned int)f2bf(fmaxf(r0.x, 0.f)) | ((unsigned int)f2bf(fmaxf(r0.y, 0.f)) << 16);
                unsigned int p1_ = (unsigned int)f2bf(fmaxf(r0.z, 0.f)) | ((unsigned int)f2bf(fmaxf(r0.w, 0.f)) << 16);
                unsigned int p2_ = (unsigned int)f2bf(fmaxf(r1.x, 0.f)) | ((unsigned int)f2bf(fmaxf(r1.y, 0.f)) << 16);
                unsigned int p3_ = (unsigned int)f2bf(fmaxf(r1.z, 0.f)) | ((unsigned int)f2bf(fmaxf(r1.w, 0.f)) << 16);
                *(uint4*)&At[i * STC + j0] = make_uint4(p0_, p1_, p2_, p3_);
            }
        }
        __syncthreads();

        int nt0 = 2 * w, nt1 = 2 * w + 1;
        f32x4 acc0[4], acc1[4];
        for (int m = 0; m < 4; ++m)
            for (int r = 0; r < 4; ++r) { acc0[m][r] = 0.f; acc1[m][r] = 0.f; }
#pragma unroll
        for (int s = 0; s < 4; ++s) {
#pragma unroll
            for (int m = 0; m < 4; ++m) {
                short8 afr = *(const short8*)&At[(m * 16 + lm) * STC + s * 32 + quad * 8];
                acc0[m] = __builtin_amdgcn_mfma_f32_16x16x32_bf16(afr, b0s[s], acc0[m], 0, 0, 0);
                acc1[m] = __builtin_amdgcn_mfma_f32_16x16x32_bf16(afr, b1s[s], acc1[m], 0, 0, 0);
            }
        }
        __syncthreads();
        for (int m = 0; m < 4; ++m)
            for (int r = 0; r < 4; ++r) {
                int rw = m * 16 + quad * 4 + r;
                At[rw * SOT + nt0 * 16 + lm] = f2bf(acc0[m][r]);
                At[rw * SOT + nt1 * 16 + lm] = f2bf(acc1[m][r]);
            }
        __syncthreads();
        for (int u = tid; u < 1024; u += 256) {
            int i = u >> 4, l = u & 15;
            if (e0 + i < E)
                *(uint4*)&Um[(size_t)posS[i] * 128 + l * 8] = *(uint4*)&At[i * SOT + l * 8];
        }
        __syncthreads();
    }
}

// ---------------- lite classifier: z1 = relu(P[src]+Q[col]+U[p]); z2; logits ----------------

__global__ __launch_bounds__(256, 6) void classifier_lite(
    const int* __restrict__ csc_src, const int2* __restrict__ csc_ec,
    const unsigned short* __restrict__ P, const unsigned short* __restrict__ Q,
    const unsigned short* __restrict__ Um,
    const unsigned short* __restrict__ Bp2, const float* __restrict__ bc2,
    const float* __restrict__ Wc3, const float* __restrict__ bc3,
    float* __restrict__ out, int E) {
    __shared__ __align__(16) unsigned char smem[19456];
    unsigned short* z1 = (unsigned short*)smem;       // [64][136] bf16
    float* z2 = (float*)smem;                         // [64][Z2S] fp32 overlay
    int* sS = (int*)(smem + 17664);
    int* eS = sS + 64;
    int* cS = eS + 64;
    float* part = (float*)(smem + 18432);             // [4][64]

    int tid = threadIdx.x;
    int p0 = blockIdx.x * 64;
    int l = tid & 15;

    // positional U loads first — independent of the idx chain, overlap its latency
    uint4 uv[4];
    {
        const uint4* U4 = (const uint4*)Um;
#pragma unroll
        for (int j = 0; j < 4; ++j) {
            int i = (tid >> 4) + 16 * j;
            uv[j] = U4[(size_t)(p0 + i) * 16 + l];
        }
    }
    if (tid < 64) {
        int p = p0 + tid; if (p >= E) p = E - 1;
        sS[tid] = csc_src[p];
        int2 ec = csc_ec[p];
        eS[tid] = ec.x; cS[tid] = ec.y;
    }
    __syncthreads();

    {
        const uint4* P4 = (const uint4*)P;
        const uint4* Q4 = (const uint4*)Q;
#pragma unroll
        for (int j = 0; j < 4; ++j) {
            int i = (tid >> 4) + 16 * j;
            uint4 pv = P4[(size_t)sS[i] * 16 + l];
            uint4 qv = Q4[(size_t)cS[i] * 16 + l];
            uint4 uvx = uv[j];
            unsigned int o0 = (unsigned int)f2bf(fmaxf(bflo(pv.x) + bflo(qv.x) + bflo(uvx.x), 0.f)) |
                              ((unsigned int)f2bf(fmaxf(bfhi(pv.x) + bfhi(qv.x) + bfhi(uvx.x), 0.f)) << 16);
            unsigned int o1 = (unsigned int)f2bf(fmaxf(bflo(pv.y) + bflo(qv.y) + bflo(uvx.y), 0.f)) |
                              ((unsigned int)f2bf(fmaxf(bfhi(pv.y) + bfhi(qv.y) + bfhi(uvx.y), 0.f)) << 16);
            unsigned int o2 = (unsigned int)f2bf(fmaxf(bflo(pv.z) + bflo(qv.z) + bflo(uvx.z), 0.f)) |
                              ((unsigned int)f2bf(fmaxf(bfhi(pv.z) + bfhi(qv.z) + bfhi(uvx.z), 0.f)) << 16);
            unsigned int o3 = (unsigned int)f2bf(fmaxf(bflo(pv.w) + bflo(qv.w) + bflo(uvx.w), 0.f)) |
                              ((unsigned int)f2bf(fmaxf(bfhi(pv.w) + bfhi(qv.w) + bfhi(uvx.w), 0.f)) << 16);
            *(uint4*)&z1[i * 136 + l * 8] = make_uint4(o0, o1, o2, o3);
        }
    }
    __syncthreads();

    int lane = tid & 63, w = tid >> 6, lm = lane & 15, quad = lane >> 4;

    f32x4 acc2[4];
    {
        float bv = bc2[w * 16 + lm];
        for (int m = 0; m < 4; ++m)
            for (int r = 0; r < 4; ++r) acc2[m][r] = bv;
#pragma unroll
        for (int s = 0; s < 4; ++s) {
            short8 b = *(const short8*)&Bp2[((size_t)(s * 4 + w) * 64 + lane) * 8];
#pragma unroll
            for (int m = 0; m < 4; ++m) {
                short8 afr = *(const short8*)&z1[(m * 16 + lm) * 136 + s * 32 + quad * 8];
                acc2[m] = __builtin_amdgcn_mfma_f32_16x16x32_bf16(afr, b, acc2[m], 0, 0, 0);
            }
        }
    }
    __syncthreads();
    for (int m = 0; m < 4; ++m)
        for (int r = 0; r < 4; ++r)
            z2[(m * 16 + quad * 4 + r) * Z2S + w * 16 + lm] = fmaxf(acc2[m][r], 0.f);
    __syncthreads();

    {
        int e = tid & 63, q = tid >> 6;
        int c = q & 1, hf = q >> 1;
        const float* zr = z2 + e * Z2S + hf * 32;
        const float* wc = Wc3 + hf * 64 + c;
        float acc = 0.f;
#pragma unroll 8
        for (int kk = 0; kk < 32; ++kk)
            acc = fmaf(zr[kk], wc[2 * kk], acc);
        part[q * 64 + e] = acc;
    }
    __syncthreads();
    if (tid < 64) {
        int p = p0 + tid;
        if (p < E) {
            float l0 = bc3[0] + part[tid] + part[128 + tid];
            float l1 = bc3[1] + part[64 + tid] + part[192 + tid];
            float m = fmaxf(l0, l1);
            float lse = m + logf(expf(l0 - m) + expf(l1 - m));
            ((float2*)out)[eS[tid]] = make_float2(l0 - lse, l1 - lse);
        }
    }
}

// ---------------- fallback fused classifier (r9) ----------------

__global__ __launch_bounds__(256, 4) void classifier_mfma(
    const int* __restrict__ csc_src, const int2* __restrict__ csc_ec,
    const float* __restrict__ ea,
    const float* __restrict__ We1, const float* __restrict__ be1,
    const unsigned short* __restrict__ P, const unsigned short* __restrict__ Q,
    const unsigned short* __restrict__ BpU, const unsigned short* __restrict__ Bp2,
    const float* __restrict__ bc2, const float* __restrict__ Wc3, const float* __restrict__ bc3,
    float* __restrict__ out, int E) {
    __shared__ __align__(16) unsigned char smem[37888];
    unsigned short* SpqB = (unsigned short*)smem;
    float* z2 = (float*)smem;
    unsigned short* At = (unsigned short*)(smem + 17664);
    unsigned short* z1 = At;
    float* part = (float*)(smem + 17664);
    int* sS = (int*)(smem + 37120);
    int* eS = sS + 64;
    int* cS = eS + 64;

    int tid = threadIdx.x;
    int lane = tid & 63, w = tid >> 6, lm = lane & 15, quad = lane >> 4;
    int e0 = blockIdx.x * 64;

    short8 b0s[4], b1s[4], b2s[4];
#pragma unroll
    for (int s = 0; s < 4; ++s) {
        b0s[s] = *(const short8*)&BpU[((size_t)(s * 8 + 2 * w) * 64 + lane) * 8];
        b1s[s] = *(const short8*)&BpU[((size_t)(s * 8 + 2 * w + 1) * 64 + lane) * 8];
        b2s[s] = *(const short8*)&Bp2[((size_t)(s * 4 + w) * 64 + lane) * 8];
    }
    float bv2 = bc2[w * 16 + lm];

    if (tid < 64) {
        int p = e0 + tid; if (p >= E) p = E - 1;
        sS[tid] = csc_src[p];
        int2 ec = csc_ec[p];
        eS[tid] = ec.x; cS[tid] = ec.y;
    }
    __syncthreads();

    {
        const uint4* P4 = (const uint4*)P;
        const uint4* Q4 = (const uint4*)Q;
        int l = tid & 15;
#pragma unroll
        for (int j = 0; j < 4; ++j) {
            int i = (tid >> 4) + 16 * j;
            uint4 pv = P4[(size_t)sS[i] * 16 + l];
            uint4 qv = Q4[(size_t)cS[i] * 16 + l];
            unsigned int o0 = (unsigned int)f2bf(bflo(pv.x) + bflo(qv.x)) |
                              ((unsigned int)f2bf(bfhi(pv.x) + bfhi(qv.x)) << 16);
            unsigned int o1 = (unsigned int)f2bf(bflo(pv.y) + bflo(qv.y)) |
                              ((unsigned int)f2bf(bfhi(pv.y) + bfhi(qv.y)) << 16);
            unsigned int o2 = (unsigned int)f2bf(bflo(pv.z) + bflo(qv.z)) |
                              ((unsigned int)f2bf(bfhi(pv.z) + bfhi(qv.z)) << 16);
            unsigned int o3 = (unsigned int)f2bf(bflo(pv.w) + bflo(qv.w)) |
                              ((unsigned int)f2bf(bfhi(pv.w) + bfhi(qv.w)) << 16);
            *(uint4*)&SpqB[i * SPQ + l * 8] = make_uint4(o0, o1, o2, o3);
        }
    }
    {
        int i = tid >> 2, jv0 = (tid & 3) * 32;
        float4 a = ((const float4*)ea)[eS[i]];
        const float4* W14 = (const float4*)We1;
        const float4* b14 = (const float4*)be1;
        for (int g = 0; g < 4; ++g) {
            int j0 = jv0 + g * 8, q = j0 >> 2;
            float4 r0 = b14[q], r1 = b14[q + 1];
            fma4(r0, a.x, W14[q]);      fma4(r1, a.x, W14[q + 1]);
            fma4(r0, a.y, W14[32 + q]); fma4(r1, a.y, W14[32 + q + 1]);
            fma4(r0, a.z, W14[64 + q]); fma4(r1, a.z, W14[64 + q + 1]);
            fma4(r0, a.w, W14[96 + q]); fma4(r1, a.w, W14[96 + q + 1]);
            unsigned int p0 = (unsigned int)f2bf(fmaxf(r0.x, 0.f)) | ((unsigned int)f2bf(fmaxf(r0.y, 0.f)) << 16);
            unsigned int p1 = (unsigned int)f2bf(fmaxf(r0.z, 0.f)) | ((unsigned int)f2bf(fmaxf(r0.w, 0.f)) << 16);
            unsigned int p2 = (unsigned int)f2bf(fmaxf(r1.x, 0.f)) | ((unsigned int)f2bf(fmaxf(r1.y, 0.f)) << 16);
            unsigned int p3 = (unsigned int)f2bf(fmaxf(r1.z, 0.f)) | ((unsigned int)f2bf(fmaxf(r1.w, 0.f)) << 16);
            *(uint4*)&At[i * STC + j0] = make_uint4(p0, p1, p2, p3);
        }
    }
    __syncthreads();

    f32x4 acc0[4], acc1[4];
    for (int m = 0; m < 4; ++m)
        for (int r = 0; r < 4; ++r) { acc0[m][r] = 0.f; acc1[m][r] = 0.f; }
#pragma unroll
    for (int s = 0; s < 4; ++s) {
#pragma unroll
        for (int m = 0; m < 4; ++m) {
            short8 afr = *(const short8*)&At[(m * 16 + lm) * STC + s * 32 + quad * 8];
            acc0[m] = __builtin_amdgcn_mfma_f32_16x16x32_bf16(afr, b0s[s], acc0[m], 0, 0, 0);
            acc1[m] = __builtin_amdgcn_mfma_f32_16x16x32_bf16(afr, b1s[s], acc1[m], 0, 0, 0);
        }
    }
    for (int m = 0; m < 4; ++m)
        for (int r = 0; r < 4; ++r) {
            int rw = m * 16 + quad * 4 + r;
            acc0[m][r] = fmaxf(acc0[m][r] + bf2f(SpqB[rw * SPQ + 32 * w + lm]), 0.f);
            acc1[m][r] = fmaxf(acc1[m][r] + bf2f(SpqB[rw * SPQ + 32 * w + 16 + lm]), 0.f);
        }
    __syncthreads();
    for (int m = 0; m < 4; ++m)
        for (int r = 0; r < 4; ++r) {
            int rw = m * 16 + quad * 4 + r;
            z1[rw * STC + 32 * w + lm]      = f2bf(acc0[m][r]);
            z1[rw * STC + 32 * w + 16 + lm] = f2bf(acc1[m][r]);
        }
    __syncthreads();

    {
        f32x4 acc2[4];
        for (int m = 0; m < 4; ++m)
            for (int r = 0; r < 4; ++r) acc2[m][r] = bv2;
#pragma unroll
        for (int s = 0; s < 4; ++s) {
#pragma unroll
            for (int m = 0; m < 4; ++m) {
                short8 afr = *(const short8*)&z1[(m * 16 + lm) * STC + s * 32 + quad * 8];
                acc2[m] = __builtin_amdgcn_mfma_f32_16x16x32_bf16(afr, b2s[s], acc2[m], 0, 0, 0);
            }
        }
        for (int m = 0; m < 4; ++m)
            for (int r = 0; r < 4; ++r)
                z2[(m * 16 + quad * 4 + r) * Z2S + w * 16 + lm] = fmaxf(acc2[m][r], 0.f);
    }
    __syncthreads();

    {
        int e = tid & 63, q = tid >> 6;
        int c = q & 1, hf = q >> 1;
        const float* zr = z2 + e * Z2S + hf * 32;
        const float* wc = Wc3 + hf * 64 + c;
        float acc = 0.f;
#pragma unroll 8
        for (int kk = 0; kk < 32; ++kk)
            acc = fmaf(zr[kk], wc[2 * kk], acc);
        part[q * 64 + e] = acc;
    }
    __syncthreads();
    if (tid < 64) {
        int p = e0 + tid;
        if (p < E) {
            float l0 = bc3[0] + part[tid] + part[128 + tid];
            float l1 = bc3[1] + part[64 + tid] + part[192 + tid];
            float m = fmaxf(l0, l1);
            float lse = m + logf(expf(l0 - m) + expf(l1 - m));
            ((float2*)out)[eS[tid]] = make_float2(l0 - lse, l1 - lse);
        }
    }
}

// ---------------- launch ----------------

extern "C" void kernel_launch(void* const* d_in, const int* in_sizes, int n_in,
                              void* d_out, int out_size, void* d_ws, size_t ws_size,
                              hipStream_t stream) {
    const float* x   = (const float*)d_in[0];
    const int*   ei  = (const int*)d_in[1];
    const float* ea  = (const float*)d_in[2];
    const float* W1  = (const float*)d_in[3];
    const float* b1  = (const float*)d_in[4];
    const float* W2  = (const float*)d_in[5];
    const float* b2  = (const float*)d_in[6];
    const float* W3  = (const float*)d_in[7];
    const float* b3  = (const float*)d_in[8];
    const float* We1 = (const float*)d_in[9];
    const float* be1 = (const float*)d_in[10];
    const float* We2 = (const float*)d_in[11];
    const float* be2 = (const float*)d_in[12];
    const float* Wc1 = (const float*)d_in[13];
    const float* bc1 = (const float*)d_in[14];
    const float* Wc2 = (const float*)d_in[15];
    const float* bc2 = (const float*)d_in[16];
    const float* Wc3 = (const float*)d_in[17];
    const float* bc3 = (const float*)d_in[18];
    float* out = (float*)d_out;

    int N = in_sizes[0] / 8;
    int E = in_sizes[1] / 2;
    const int* row = ei;
    const int* col = ei + E;
    int NB = (N + 1023) / 1024;
    int ntiles = (E + 63) / 64;

    char* w = (char*)d_ws;
    auto alloc = [&](size_t bytes) { void* p = (void*)w; w += (bytes + 255) & ~(size_t)255; return p; };
    int*   cnt       = (int*)alloc((size_t)N * 4);
    int*   col_start = (int*)alloc((size_t)(N + 1) * 4);
    int*   cursor    = (int*)alloc((size_t)N * 4);
    int*   csc_src   = (int*)alloc((size_t)E * 4);
    int2*  csc_ec    = (int2*)alloc((size_t)E * 8);
    int*   csc_pos   = (int*)alloc((size_t)E * 4);
    float* dinv      = (float*)alloc((size_t)N * 4);
    int*   bsum      = (int*)alloc(64 * 4);
    int*   boff      = (int*)alloc(64 * 4);
    float* Weff      = (float*)alloc(128 * 128 * 4);
    float* bc1p      = (float*)alloc(128 * 4);
    unsigned short* BpA  = (unsigned short*)alloc(32768);
    unsigned short* BpB  = (unsigned short*)alloc(32768);
    unsigned short* BpU  = (unsigned short*)alloc(32768);
    unsigned short* BpW2 = (unsigned short*)alloc(32768);
    unsigned short* BpW3 = (unsigned short*)alloc(32768);
    unsigned short* Bp2  = (unsigned short*)alloc(16384);
    float* aggx = (float*)alloc((size_t)N * 8 * 4);
    // P/Q BEFORE the GCN feature buffers so Um can overlay bufA/bufB (dead after h3pq)
    unsigned short* Pm   = (unsigned short*)alloc((size_t)N * H * 2);
    unsigned short* Qm   = (unsigned short*)alloc((size_t)N * H * 2);
    size_t bufA_off = (size_t)(w - (char*)d_ws);
    unsigned short* bufA = (unsigned short*)alloc((size_t)N * H * 2);
    unsigned short* bufB = (unsigned short*)alloc((size_t)N * H * 2);

    // Um overlays bufA/bufB + extends into free space: valid only AFTER h3pq (last bufB reader)
    size_t umBytes = (size_t)ntiles * 64 * H * 2;
    bool useU = (bufA_off + umBytes) <= ws_size;
    unsigned short* Um = (unsigned short*)((char*)d_ws + bufA_off);

    // graph build (CSC with eid+col+pos)
    hipMemsetAsync(cnt, 0, (size_t)N * 4, stream);
    count_kernel<<<(E + 255) / 256, 256, 0, stream>>>(col, E, cnt);
    scan_sum_kernel<<<NB, 256, 0, stream>>>(cnt, N, bsum);
    scan_offsets_kernel<<<1, 64, 0, stream>>>(bsum, NB, boff, col_start, N);
    scan_write_kernel<<<NB, 256, 0, stream>>>(cnt, N, boff, col_start, cursor, dinv);
    scatter_kernel<<<(E + 255) / 256, 256, 0, stream>>>(row, col, E, cursor, csc_src, csc_ec, csc_pos);

    // weight prep
    weff_kernel<<<64, 256, 0, stream>>>(We2, Wc1, Weff);
    bc1p_kernel<<<1, 128, 0, stream>>>(bc1, be2, Wc1, bc1p);
    packg_kernel<<<8, 256, 0, stream>>>(Wc1, BpA);
    packg_kernel<<<8, 256, 0, stream>>>(Wc1 + 128 * 128, BpB);
    packg_kernel<<<8, 256, 0, stream>>>(Weff, BpU);
    packg_kernel<<<8, 256, 0, stream>>>(W2, BpW2);
    packg_kernel<<<8, 256, 0, stream>>>(W3, BpW3);
    pack2_kernel<<<4, 256, 0, stream>>>(Wc2, Bp2);

    // GCN: aggregate-then-transform, dinv-prescaled bf16 features
    aggx_kernel<<<(N * 8 + 255) / 256, 256, 0, stream>>>(x, col_start, csc_src, dinv, aggx, N);
    xform8bf_kernel<<<(N * 64 + 255) / 256, 256, 0, stream>>>(aggx, W1, b1, dinv,
                                                              (unsigned int*)bufA, N);   // h1d
    agg128bf_kernel<<<(N + 3) / 4, 256, 0, stream>>>((const unsigned int*)bufA, col_start, csc_src,
                                                     dinv, (unsigned int*)bufB, N);      // agg2
    xform_mfma_kernel<<<(N + 63) / 64, 256, 0, stream>>>(bufB, BpW2, b2, dinv, bufA, N); // h2d
    agg128bf_kernel<<<(N + 3) / 4, 256, 0, stream>>>((const unsigned int*)bufA, col_start, csc_src,
                                                     dinv, (unsigned int*)bufB, N);      // agg3
    h3pq_kernel<<<(N + 63) / 64, 256, 0, stream>>>(bufB, BpW3, b3, BpA, BpB, bc1p, Pm, Qm, N);

    if (useU) {
        // bufA/bufB now dead — Um may overwrite them
        ucompute2_kernel<<<(ntiles + 3) / 4, 256, 0, stream>>>(csc_pos, ea, We1, be1, BpU, Um, E);
        classifier_lite<<<ntiles, 256, 0, stream>>>(
            csc_src, csc_ec, Pm, Qm, Um, Bp2, bc2, Wc3, bc3, out, E);
    } else {
        classifier_mfma<<<ntiles, 256, 0, stream>>>(
            csc_src, csc_ec, ea, We1, be1, Pm, Qm, BpU, Bp2, bc2, Wc3, bc3, out, E);
    }
}

// Round 12
// 477.068 us; speedup vs baseline: 1.4771x; 1.4771x over previous
//
#include <hip/hip_runtime.h>
#include <math.h>

#define H 128
#define STC 152   // LDS stride (shorts) for bf16 A-tiles
#define SOT 136   // LDS stride (shorts) for staged bf16 output tiles
#define SPQ 136   // LDS stride (shorts) for bf16 Spq
#define Z2S 69    // LDS stride (floats) for z2

typedef __attribute__((ext_vector_type(8))) short short8;
typedef __attribute__((ext_vector_type(4))) float f32x4;

__device__ inline unsigned short f2bf(float f) {
    unsigned int u = __float_as_uint(f);
    return (unsigned short)((u + 0x7fffu + ((u >> 16) & 1u)) >> 16);
}
__device__ inline float bflo(unsigned int v) { return __uint_as_float(v << 16); }
__device__ inline float bfhi(unsigned int v) { return __uint_as_float(v & 0xffff0000u); }
__device__ inline float bf2f(unsigned short v) { return __uint_as_float(((unsigned int)v) << 16); }

__device__ inline void fma4(float4& acc, float a, const float4 w) {
    acc.x = fmaf(a, w.x, acc.x);
    acc.y = fmaf(a, w.y, acc.y);
    acc.z = fmaf(a, w.z, acc.z);
    acc.w = fmaf(a, w.w, acc.w);
}

// ---------------- graph build ----------------

__global__ void count_kernel(const int* __restrict__ col, int E, int* __restrict__ cnt) {
    int e = blockIdx.x * blockDim.x + threadIdx.x;
    if (e < E) atomicAdd(&cnt[col[e]], 1);
}

__global__ void scan_sum_kernel(const int* __restrict__ cnt, int N, int* __restrict__ bsum) {
    int b = blockIdx.x, t = threadIdx.x;
    int base = b * 1024 + t * 4;
    int s = 0;
#pragma unroll
    for (int g = 0; g < 4; ++g) {
        int i = base + g;
        if (i < N) s += cnt[i];
    }
    for (int off = 32; off >= 1; off >>= 1) s += __shfl_down(s, off, 64);
    __shared__ int ws[4];
    if ((t & 63) == 0) ws[t >> 6] = s;
    __syncthreads();
    if (t == 0) bsum[b] = ws[0] + ws[1] + ws[2] + ws[3];
}

__global__ void scan_offsets_kernel(const int* __restrict__ bsum, int nb,
                                    int* __restrict__ boff, int* __restrict__ col_start, int N) {
    int lane = threadIdx.x;
    int v = (lane < nb) ? bsum[lane] : 0;
    int incl = v;
    for (int off = 1; off < 64; off <<= 1) {
        int u = __shfl_up(incl, off, 64);
        if (lane >= off) incl += u;
    }
    if (lane < nb) boff[lane] = incl - v;
    if (lane == 63) col_start[N] = incl;
}

__global__ void scan_write_kernel(const int* __restrict__ cnt, int N, const int* __restrict__ boff,
                                  int* __restrict__ col_start, int* __restrict__ cursor,
                                  float* __restrict__ dinv) {
    int b = blockIdx.x, t = threadIdx.x;
    int lane = t & 63, wv = t >> 6;
    int base = b * 1024 + t * 4;
    int c[4];
    int s = 0;
#pragma unroll
    for (int g = 0; g < 4; ++g) {
        int i = base + g;
        c[g] = (i < N) ? cnt[i] : 0;
        s += c[g];
    }
    int incl = s;
    for (int off = 1; off < 64; off <<= 1) {
        int u = __shfl_up(incl, off, 64);
        if (lane >= off) incl += u;
    }
    __shared__ int ws[4];
    if (lane == 63) ws[wv] = incl;
    __syncthreads();
    int run = boff[b] + incl - s;
    for (int w = 0; w < wv; ++w) run += ws[w];
#pragma unroll
    for (int g = 0; g < 4; ++g) {
        int i = base + g;
        if (i < N) {
            col_start[i] = run;
            cursor[i] = run;
            dinv[i] = rsqrtf((float)(c[g] + 1));
            run += c[g];
        }
    }
}

__global__ void scatter_kernel(const int* __restrict__ row, const int* __restrict__ col, int E,
                               int* __restrict__ cursor, int* __restrict__ csc_src,
                               int2* __restrict__ csc_ec) {
    int e = blockIdx.x * blockDim.x + threadIdx.x;
    if (e < E) {
        int c = col[e];
        int p = atomicAdd(&cursor[c], 1);
        csc_src[p] = row[e];
        csc_ec[p] = make_int2(e, c);
    }
}

// ---------------- GCN: aggregate-then-transform (bf16 dinv-prescaled features) ----------------

__global__ void aggx_kernel(const float* __restrict__ x, const int* __restrict__ col_start,
                            const int* __restrict__ csc_src, const float* __restrict__ dinv,
                            float* __restrict__ aggx, int N) {
    int t = blockIdx.x * blockDim.x + threadIdx.x;
    int i = t >> 3, f = t & 7;
    if (i >= N) return;
    int s0 = col_start[i], s1 = col_start[i + 1];
    float acc = 0.f;
    for (int p = s0; p < s1; ++p) {
        int s = csc_src[p];
        acc = fmaf(dinv[s], x[s * 8 + f], acc);
    }
    float di = dinv[i];
    aggx[i * 8 + f] = fmaf(di, acc, di * di * x[i * 8 + f]);
}

__global__ void xform8bf_kernel(const float* __restrict__ aggx, const float* __restrict__ W,
                                const float* __restrict__ b, const float* __restrict__ dinv,
                                unsigned int* __restrict__ out, int N) {
    int t = blockIdx.x * 256 + threadIdx.x;
    int i = t >> 6, jp = t & 63;
    if (i >= N) return;
    const float* ar = aggx + i * 8;
    float sc = dinv[i];
    int j0 = jp * 2;
    float a0 = b[j0], a1 = b[j0 + 1];
#pragma unroll
    for (int k = 0; k < 8; ++k) {
        float av = ar[k];
        a0 = fmaf(av, W[k * 128 + j0], a0);
        a1 = fmaf(av, W[k * 128 + j0 + 1], a1);
    }
    out[(size_t)i * 64 + jp] = (unsigned int)f2bf(sc * fmaxf(a0, 0.f)) |
                               ((unsigned int)f2bf(sc * fmaxf(a1, 0.f)) << 16);
}

__global__ __launch_bounds__(256) void agg128bf_kernel(
    const unsigned int* __restrict__ hd, const int* __restrict__ col_start,
    const int* __restrict__ csc_src, const float* __restrict__ dinv,
    unsigned int* __restrict__ out, int N) {
    int wv = threadIdx.x >> 6, lane = threadIdx.x & 63;
    int i = blockIdx.x * 4 + wv;
    if (i >= N) return;
    int s0 = col_start[i], s1 = col_start[i + 1];
    float ax = 0.f, ay = 0.f;
    int p = s0;
    for (; p + 8 <= s1; p += 8) {
        unsigned int v0 = hd[(size_t)csc_src[p + 0] * 64 + lane];
        unsigned int v1 = hd[(size_t)csc_src[p + 1] * 64 + lane];
        unsigned int v2 = hd[(size_t)csc_src[p + 2] * 64 + lane];
        unsigned int v3 = hd[(size_t)csc_src[p + 3] * 64 + lane];
        unsigned int v4 = hd[(size_t)csc_src[p + 4] * 64 + lane];
        unsigned int v5 = hd[(size_t)csc_src[p + 5] * 64 + lane];
        unsigned int v6 = hd[(size_t)csc_src[p + 6] * 64 + lane];
        unsigned int v7 = hd[(size_t)csc_src[p + 7] * 64 + lane];
        ax += bflo(v0) + bflo(v1) + bflo(v2) + bflo(v3) + bflo(v4) + bflo(v5) + bflo(v6) + bflo(v7);
        ay += bfhi(v0) + bfhi(v1) + bfhi(v2) + bfhi(v3) + bfhi(v4) + bfhi(v5) + bfhi(v6) + bfhi(v7);
    }
    for (; p < s1; ++p) {
        unsigned int v = hd[(size_t)csc_src[p] * 64 + lane];
        ax += bflo(v); ay += bfhi(v);
    }
    float di = dinv[i];
    unsigned int vs = hd[(size_t)i * 64 + lane];
    float rx = di * (ax + bflo(vs));
    float ry = di * (ay + bfhi(vs));
    out[(size_t)i * 64 + lane] = (unsigned int)f2bf(rx) | ((unsigned int)f2bf(ry) << 16);
}

__global__ __launch_bounds__(256) void xform_mfma_kernel(
    const unsigned short* __restrict__ in, const unsigned short* __restrict__ Bp,
    const float* __restrict__ b, const float* __restrict__ scale,
    unsigned short* __restrict__ out, int N) {
    __shared__ __align__(16) unsigned short sm[64 * STC];
    int tid = threadIdx.x;
    int i0 = blockIdx.x * 64;
    for (int u = tid; u < 1024; u += 256) {
        int i = u >> 4, l = u & 15;
        int node = i0 + i; if (node >= N) node = N - 1;
        uint4 v = ((const uint4*)in)[(size_t)node * 16 + l];
        *(uint4*)&sm[i * STC + l * 8] = v;
    }
    __syncthreads();
    int lane = tid & 63, w = tid >> 6, lm = lane & 15, quad = lane >> 4;
    int nt0 = 2 * w, nt1 = 2 * w + 1;
    f32x4 acc0[4], acc1[4];
    {
        float bv0 = b[nt0 * 16 + lm], bv1 = b[nt1 * 16 + lm];
        for (int m = 0; m < 4; ++m)
            for (int r = 0; r < 4; ++r) { acc0[m][r] = bv0; acc1[m][r] = bv1; }
    }
#pragma unroll
    for (int s = 0; s < 4; ++s) {
        short8 b0 = *(const short8*)&Bp[((size_t)(s * 8 + nt0) * 64 + lane) * 8];
        short8 b1 = *(const short8*)&Bp[((size_t)(s * 8 + nt1) * 64 + lane) * 8];
#pragma unroll
        for (int m = 0; m < 4; ++m) {
            short8 afr = *(const short8*)&sm[(m * 16 + lm) * STC + s * 32 + quad * 8];
            acc0[m] = __builtin_amdgcn_mfma_f32_16x16x32_bf16(afr, b0, acc0[m], 0, 0, 0);
            acc1[m] = __builtin_amdgcn_mfma_f32_16x16x32_bf16(afr, b1, acc1[m], 0, 0, 0);
        }
    }
    __syncthreads();
    for (int m = 0; m < 4; ++m)
        for (int r = 0; r < 4; ++r) {
            int rw = m * 16 + quad * 4 + r;
            int node = i0 + rw; if (node >= N) node = N - 1;
            float sc = scale ? scale[node] : 1.f;
            sm[rw * SOT + nt0 * 16 + lm] = f2bf(sc * fmaxf(acc0[m][r], 0.f));
            sm[rw * SOT + nt1 * 16 + lm] = f2bf(sc * fmaxf(acc1[m][r], 0.f));
        }
    __syncthreads();
    for (int u = tid; u < 1024; u += 256) {
        int i = u >> 4, l = u & 15;
        int node = i0 + i;
        if (node < N)
            *(uint4*)&out[(size_t)node * 128 + l * 8] = *(uint4*)&sm[i * SOT + l * 8];
    }
}

// ---------------- classifier weight prep ----------------

__global__ void weff_kernel(const float* __restrict__ We2, const float* __restrict__ Wc1,
                            float* __restrict__ Weff) {
    int idx = blockIdx.x * blockDim.x + threadIdx.x;
    int k = idx >> 7, c = idx & 127;
    float acc = 0.f;
    for (int j = 0; j < 128; ++j)
        acc = fmaf(We2[k * 128 + j], Wc1[(256 + j) * 128 + c], acc);
    Weff[idx] = acc;
}

__global__ void bc1p_kernel(const float* __restrict__ bc1, const float* __restrict__ be2,
                            const float* __restrict__ Wc1, float* __restrict__ bc1p) {
    int c = threadIdx.x;
    float acc = bc1[c];
    for (int j = 0; j < 128; ++j)
        acc = fmaf(be2[j], Wc1[(256 + j) * 128 + c], acc);
    bc1p[c] = acc;
}

__global__ void packg_kernel(const float* __restrict__ src, unsigned short* __restrict__ dst) {
    int idx = blockIdx.x * 256 + threadIdx.x;  // 2048
    int s = idx >> 9, nt = (idx >> 6) & 7, lane = idx & 63;
    int quad = lane >> 4, lm = lane & 15;
    int n = nt * 16 + lm, k0 = s * 32 + quad * 8;
    unsigned int p[4];
#pragma unroll
    for (int g = 0; g < 4; ++g) {
        p[g] = (unsigned int)f2bf(src[(k0 + 2 * g) * 128 + n]) |
               ((unsigned int)f2bf(src[(k0 + 2 * g + 1) * 128 + n]) << 16);
    }
    *(uint4*)&dst[(size_t)idx * 8] = make_uint4(p[0], p[1], p[2], p[3]);
}

__global__ void pack2_kernel(const float* __restrict__ Wc2, unsigned short* __restrict__ Bp2) {
    int idx = blockIdx.x * 256 + threadIdx.x;  // 1024
    int s = idx >> 8, nt = (idx >> 6) & 3, lane = idx & 63;
    int quad = lane >> 4, lm = lane & 15;
    int n = nt * 16 + lm, k0 = s * 32 + quad * 8;
    unsigned int p[4];
#pragma unroll
    for (int g = 0; g < 4; ++g) {
        p[g] = (unsigned int)f2bf(Wc2[(k0 + 2 * g) * 64 + n]) |
               ((unsigned int)f2bf(Wc2[(k0 + 2 * g + 1) * 64 + n]) << 16);
    }
    *(uint4*)&Bp2[(size_t)idx * 8] = make_uint4(p[0], p[1], p[2], p[3]);
}

// pack We1_ext (rows 0..3 = We1, row 4 = be1, rows 5..31 = 0) into one K-step of
// 16x16x32 B-fragments: BpE[nt<8][lane<64][8]
__global__ void packwe1_kernel(const float* __restrict__ We1, const float* __restrict__ be1,
                               unsigned short* __restrict__ BpE) {
    int idx = blockIdx.x * 256 + threadIdx.x;  // 512
    if (idx >= 512) return;
    int nt = idx >> 6, lane = idx & 63;
    int quad = lane >> 4, lm = lane & 15;
    int n = nt * 16 + lm, k0 = quad * 8;
    unsigned int p[4];
#pragma unroll
    for (int g = 0; g < 4; ++g) {
        int r0 = k0 + 2 * g, r1 = r0 + 1;
        float v0 = (r0 < 4) ? We1[r0 * 128 + n] : ((r0 == 4) ? be1[n] : 0.f);
        float v1 = (r1 < 4) ? We1[r1 * 128 + n] : ((r1 == 4) ? be1[n] : 0.f);
        p[g] = (unsigned int)f2bf(v0) | ((unsigned int)f2bf(v1) << 16);
    }
    *(uint4*)&BpE[(size_t)idx * 8] = make_uint4(p[0], p[1], p[2], p[3]);
}

// ---------------- fused h3 transform + P/Q precompute ----------------

__global__ __launch_bounds__(256) void h3pq_kernel(
    const unsigned short* __restrict__ in, const unsigned short* __restrict__ BpW3,
    const float* __restrict__ b3,
    const unsigned short* __restrict__ BpA, const unsigned short* __restrict__ BpB,
    const float* __restrict__ bc1p,
    unsigned short* __restrict__ P, unsigned short* __restrict__ Q, int N) {
    __shared__ __align__(16) unsigned short At[64 * STC];
    __shared__ __align__(16) unsigned short Hs[64 * SOT];
    int tid = threadIdx.x;
    int i0 = blockIdx.x * 64;
    for (int u = tid; u < 1024; u += 256) {
        int i = u >> 4, l = u & 15;
        int node = i0 + i; if (node >= N) node = N - 1;
        uint4 v = ((const uint4*)in)[(size_t)node * 16 + l];
        *(uint4*)&At[i * STC + l * 8] = v;
    }
    __syncthreads();
    int lane = tid & 63, w = tid >> 6, lm = lane & 15, quad = lane >> 4;

    {
        int nt0 = 2 * w, nt1 = 2 * w + 1;
        f32x4 a0[4], a1[4];
        float bv0 = b3[nt0 * 16 + lm], bv1 = b3[nt1 * 16 + lm];
        for (int m = 0; m < 4; ++m)
            for (int r = 0; r < 4; ++r) { a0[m][r] = bv0; a1[m][r] = bv1; }
#pragma unroll
        for (int s = 0; s < 4; ++s) {
            short8 b0 = *(const short8*)&BpW3[((size_t)(s * 8 + nt0) * 64 + lane) * 8];
            short8 b1 = *(const short8*)&BpW3[((size_t)(s * 8 + nt1) * 64 + lane) * 8];
#pragma unroll
            for (int m = 0; m < 4; ++m) {
                short8 afr = *(const short8*)&At[(m * 16 + lm) * STC + s * 32 + quad * 8];
                a0[m] = __builtin_amdgcn_mfma_f32_16x16x32_bf16(afr, b0, a0[m], 0, 0, 0);
                a1[m] = __builtin_amdgcn_mfma_f32_16x16x32_bf16(afr, b1, a1[m], 0, 0, 0);
            }
        }
        __syncthreads();
        for (int m = 0; m < 4; ++m)
            for (int r = 0; r < 4; ++r) {
                int rw = m * 16 + quad * 4 + r;
                Hs[rw * SOT + nt0 * 16 + lm] = f2bf(fmaxf(a0[m][r], 0.f));
                Hs[rw * SOT + nt1 * 16 + lm] = f2bf(fmaxf(a1[m][r], 0.f));
            }
    }
    __syncthreads();

    int half = w & 1;
    const unsigned short* Bp = (w >> 1) ? BpB : BpA;
    f32x4 acc[4][4];
    for (int nt = 0; nt < 4; ++nt) {
        float bv = (w >> 1) ? 0.f : bc1p[half * 64 + nt * 16 + lm];
        for (int m = 0; m < 4; ++m)
            for (int r = 0; r < 4; ++r) acc[nt][m][r] = bv;
    }
#pragma unroll
    for (int s = 0; s < 4; ++s) {
        short8 afr[4];
#pragma unroll
        for (int m = 0; m < 4; ++m)
            afr[m] = *(const short8*)&Hs[(m * 16 + lm) * SOT + s * 32 + quad * 8];
#pragma unroll
        for (int nt = 0; nt < 4; ++nt) {
            short8 bfr = *(const short8*)&Bp[((size_t)(s * 8 + half * 4 + nt) * 64 + lane) * 8];
#pragma unroll
            for (int m = 0; m < 4; ++m)
                acc[nt][m] = __builtin_amdgcn_mfma_f32_16x16x32_bf16(afr[m], bfr, acc[nt][m], 0, 0, 0);
        }
    }
    __syncthreads();
    unsigned short* St = At;

    if (w < 2) {
        for (int nt = 0; nt < 4; ++nt)
            for (int m = 0; m < 4; ++m)
                for (int r = 0; r < 4; ++r) {
                    int rw = m * 16 + quad * 4 + r;
                    St[rw * SOT + half * 64 + nt * 16 + lm] = f2bf(acc[nt][m][r]);
                }
    }
    __syncthreads();
    for (int u = tid; u < 1024; u += 256) {
        int i = u >> 4, l = u & 15;
        int node = i0 + i;
        if (node < N)
            *(uint4*)&P[(size_t)node * 128 + l * 8] = *(uint4*)&St[i * SOT + l * 8];
    }
    __syncthreads();
    if (w >= 2) {
        for (int nt = 0; nt < 4; ++nt)
            for (int m = 0; m < 4; ++m)
                for (int r = 0; r < 4; ++r) {
                    int rw = m * 16 + quad * 4 + r;
                    St[rw * SOT + half * 64 + nt * 16 + lm] = f2bf(acc[nt][m][r]);
                }
    }
    __syncthreads();
    for (int u = tid; u < 1024; u += 256) {
        int i = u >> 4, l = u & 15;
        int node = i0 + i;
        if (node < N)
            *(uint4*)&Q[(size_t)node * 128 + l * 8] = *(uint4*)&St[i * SOT + l * 8];
    }
}

// ---------------- fused classifier, all-MFMA (t-MLP via padded K=32 MFMA) ----------------

__global__ __launch_bounds__(256, 4) void classifier_mfma2(
    const int* __restrict__ csc_src, const int2* __restrict__ csc_ec,
    const float* __restrict__ ea, const unsigned short* __restrict__ BpE,
    const unsigned short* __restrict__ P, const unsigned short* __restrict__ Q,
    const unsigned short* __restrict__ BpU, const unsigned short* __restrict__ Bp2,
    const float* __restrict__ bc2, const float* __restrict__ Wc3, const float* __restrict__ bc3,
    float* __restrict__ out, int E) {
    __shared__ __align__(16) unsigned char smem[37888];
    unsigned short* SpqB = (unsigned short*)smem;         // [64][SPQ] bf16
    float* z2 = (float*)smem;                             // [64][Z2S] fp32 (overlay)
    unsigned short* At = (unsigned short*)(smem + 17664); // [64][STC] bf16 (t, then z1)
    unsigned short* z1 = At;                              // overlay
    float* part = (float*)(smem + 17664);                 // [4][64] (overlay)
    int* sS = (int*)(smem + 37120);
    int* eS = sS + 64;
    int* cS = eS + 64;

    int tid = threadIdx.x;
    int lane = tid & 63, w = tid >> 6, lm = lane & 15, quad = lane >> 4;
    int e0 = blockIdx.x * 64;

    // hoist all B-fragments (tile-invariant; L2 loads overlap idx/gather latency)
    short8 bE0 = *(const short8*)&BpE[((size_t)(2 * w) * 64 + lane) * 8];
    short8 bE1 = *(const short8*)&BpE[((size_t)(2 * w + 1) * 64 + lane) * 8];
    short8 b0s[4], b1s[4], b2s[4];
#pragma unroll
    for (int s = 0; s < 4; ++s) {
        b0s[s] = *(const short8*)&BpU[((size_t)(s * 8 + 2 * w) * 64 + lane) * 8];
        b1s[s] = *(const short8*)&BpU[((size_t)(s * 8 + 2 * w + 1) * 64 + lane) * 8];
        b2s[s] = *(const short8*)&Bp2[((size_t)(s * 4 + w) * 64 + lane) * 8];
    }
    float bv2 = bc2[w * 16 + lm];

    if (tid < 64) {
        int p = e0 + tid; if (p >= E) p = E - 1;
        sS[tid] = csc_src[p];
        int2 ec = csc_ec[p];
        eS[tid] = ec.x; cS[tid] = ec.y;
    }
    __syncthreads();

    // stage Spq = bf16(P[src] + Q[col]); col sorted -> Q reads L1/L2-friendly
    {
        const uint4* P4 = (const uint4*)P;
        const uint4* Q4 = (const uint4*)Q;
        int l = tid & 15;
#pragma unroll
        for (int j = 0; j < 4; ++j) {
            int i = (tid >> 4) + 16 * j;
            uint4 pv = P4[(size_t)sS[i] * 16 + l];
            uint4 qv = Q4[(size_t)cS[i] * 16 + l];
            unsigned int o0 = (unsigned int)f2bf(bflo(pv.x) + bflo(qv.x)) |
                              ((unsigned int)f2bf(bfhi(pv.x) + bfhi(qv.x)) << 16);
            unsigned int o1 = (unsigned int)f2bf(bflo(pv.y) + bflo(qv.y)) |
                              ((unsigned int)f2bf(bfhi(pv.y) + bfhi(qv.y)) << 16);
            unsigned int o2 = (unsigned int)f2bf(bflo(pv.z) + bflo(qv.z)) |
                              ((unsigned int)f2bf(bfhi(pv.z) + bfhi(qv.z)) << 16);
            unsigned int o3 = (unsigned int)f2bf(bflo(pv.w) + bflo(qv.w)) |
                              ((unsigned int)f2bf(bfhi(pv.w) + bfhi(qv.w)) << 16);
            *(uint4*)&SpqB[i * SPQ + l * 8] = make_uint4(o0, o1, o2, o3);
        }
    }

    // build A-fragments for t-MFMA in registers: A[edge][k], k0..3 = ea, k4 = 1 (bias row)
    short8 eaf[4];
#pragma unroll
    for (int m = 0; m < 4; ++m) eaf[m] = (short8){0, 0, 0, 0, 0, 0, 0, 0};
    if (quad == 0) {
#pragma unroll
        for (int m = 0; m < 4; ++m) {
            int ed = eS[m * 16 + lm];
            float4 a = ((const float4*)ea)[ed];
            eaf[m][0] = (short)f2bf(a.x);
            eaf[m][1] = (short)f2bf(a.y);
            eaf[m][2] = (short)f2bf(a.z);
            eaf[m][3] = (short)f2bf(a.w);
            eaf[m][4] = (short)0x3F80;  // 1.0 bf16
        }
    }

    // t = relu([ea,1] @ We1_ext) via 8 MFMAs; store to At in A-layout
    {
        f32x4 zacc = {0.f, 0.f, 0.f, 0.f};
#pragma unroll
        for (int m = 0; m < 4; ++m) {
            f32x4 t0 = __builtin_amdgcn_mfma_f32_16x16x32_bf16(eaf[m], bE0, zacc, 0, 0, 0);
            f32x4 t1 = __builtin_amdgcn_mfma_f32_16x16x32_bf16(eaf[m], bE1, zacc, 0, 0, 0);
#pragma unroll
            for (int r = 0; r < 4; ++r) {
                int rw = m * 16 + quad * 4 + r;
                At[rw * STC + 32 * w + lm]      = f2bf(fmaxf(t0[r], 0.f));
                At[rw * STC + 32 * w + 16 + lm] = f2bf(fmaxf(t1[r], 0.f));
            }
        }
    }
    __syncthreads();  // t + Spq visible

    // GEMM_t: U = t @ Weff (K=128); B-frags register-resident
    f32x4 acc0[4], acc1[4];
    for (int m = 0; m < 4; ++m)
        for (int r = 0; r < 4; ++r) { acc0[m][r] = 0.f; acc1[m][r] = 0.f; }
#pragma unroll
    for (int s = 0; s < 4; ++s) {
#pragma unroll
        for (int m = 0; m < 4; ++m) {
            short8 afr = *(const short8*)&At[(m * 16 + lm) * STC + s * 32 + quad * 8];
            acc0[m] = __builtin_amdgcn_mfma_f32_16x16x32_bf16(afr, b0s[s], acc0[m], 0, 0, 0);
            acc1[m] = __builtin_amdgcn_mfma_f32_16x16x32_bf16(afr, b1s[s], acc1[m], 0, 0, 0);
        }
    }
    // z1 = relu(U + Spq)
    for (int m = 0; m < 4; ++m)
        for (int r = 0; r < 4; ++r) {
            int rw = m * 16 + quad * 4 + r;
            acc0[m][r] = fmaxf(acc0[m][r] + bf2f(SpqB[rw * SPQ + 32 * w + lm]), 0.f);
            acc1[m][r] = fmaxf(acc1[m][r] + bf2f(SpqB[rw * SPQ + 32 * w + 16 + lm]), 0.f);
        }
    __syncthreads();
    for (int m = 0; m < 4; ++m)
        for (int r = 0; r < 4; ++r) {
            int rw = m * 16 + quad * 4 + r;
            z1[rw * STC + 32 * w + lm]      = f2bf(acc0[m][r]);
            z1[rw * STC + 32 * w + 16 + lm] = f2bf(acc1[m][r]);
        }
    __syncthreads();

    // GEMM2: z2 = relu(z1 @ Wc2 + bc2)
    {
        f32x4 acc2[4];
        for (int m = 0; m < 4; ++m)
            for (int r = 0; r < 4; ++r) acc2[m][r] = bv2;
#pragma unroll
        for (int s = 0; s < 4; ++s) {
#pragma unroll
            for (int m = 0; m < 4; ++m) {
                short8 afr = *(const short8*)&z1[(m * 16 + lm) * STC + s * 32 + quad * 8];
                acc2[m] = __builtin_amdgcn_mfma_f32_16x16x32_bf16(afr, b2s[s], acc2[m], 0, 0, 0);
            }
        }
        for (int m = 0; m < 4; ++m)
            for (int r = 0; r < 4; ++r)
                z2[(m * 16 + quad * 4 + r) * Z2S + w * 16 + lm] = fmaxf(acc2[m][r], 0.f);
    }
    __syncthreads();

    // logits: split 64-dot over 4 waves
    {
        int e = tid & 63, q = tid >> 6;
        int c = q & 1, hf = q >> 1;
        const float* zr = z2 + e * Z2S + hf * 32;
        const float* wc = Wc3 + hf * 64 + c;
        float acc = 0.f;
#pragma unroll 8
        for (int kk = 0; kk < 32; ++kk)
            acc = fmaf(zr[kk], wc[2 * kk], acc);
        part[q * 64 + e] = acc;
    }
    __syncthreads();
    if (tid < 64) {
        int p = e0 + tid;
        if (p < E) {
            float l0 = bc3[0] + part[tid] + part[128 + tid];
            float l1 = bc3[1] + part[64 + tid] + part[192 + tid];
            float m = fmaxf(l0, l1);
            float lse = m + logf(expf(l0 - m) + expf(l1 - m));
            ((float2*)out)[eS[tid]] = make_float2(l0 - lse, l1 - lse);
        }
    }
}

// ---------------- launch ----------------

extern "C" void kernel_launch(void* const* d_in, const int* in_sizes, int n_in,
                              void* d_out, int out_size, void* d_ws, size_t ws_size,
                              hipStream_t stream) {
    const float* x   = (const float*)d_in[0];
    const int*   ei  = (const int*)d_in[1];
    const float* ea  = (const float*)d_in[2];
    const float* W1  = (const float*)d_in[3];
    const float* b1  = (const float*)d_in[4];
    const float* W2  = (const float*)d_in[5];
    const float* b2  = (const float*)d_in[6];
    const float* W3  = (const float*)d_in[7];
    const float* b3  = (const float*)d_in[8];
    const float* We1 = (const float*)d_in[9];
    const float* be1 = (const float*)d_in[10];
    const float* We2 = (const float*)d_in[11];
    const float* be2 = (const float*)d_in[12];
    const float* Wc1 = (const float*)d_in[13];
    const float* bc1 = (const float*)d_in[14];
    const float* Wc2 = (const float*)d_in[15];
    const float* bc2 = (const float*)d_in[16];
    const float* Wc3 = (const float*)d_in[17];
    const float* bc3 = (const float*)d_in[18];
    float* out = (float*)d_out;

    int N = in_sizes[0] / 8;
    int E = in_sizes[1] / 2;
    const int* row = ei;
    const int* col = ei + E;
    int NB = (N + 1023) / 1024;
    int ntiles = (E + 63) / 64;

    char* w = (char*)d_ws;
    auto alloc = [&](size_t bytes) { void* p = (void*)w; w += (bytes + 255) & ~(size_t)255; return p; };
    int*   cnt       = (int*)alloc((size_t)N * 4);
    int*   col_start = (int*)alloc((size_t)(N + 1) * 4);
    int*   cursor    = (int*)alloc((size_t)N * 4);
    int*   csc_src   = (int*)alloc((size_t)E * 4);
    int2*  csc_ec    = (int2*)alloc((size_t)E * 8);
    float* dinv      = (float*)alloc((size_t)N * 4);
    int*   bsum      = (int*)alloc(64 * 4);
    int*   boff      = (int*)alloc(64 * 4);
    float* Weff      = (float*)alloc(128 * 128 * 4);
    float* bc1p      = (float*)alloc(128 * 4);
    unsigned short* BpA  = (unsigned short*)alloc(32768);
    unsigned short* BpB  = (unsigned short*)alloc(32768);
    unsigned short* BpU  = (unsigned short*)alloc(32768);
    unsigned short* BpW2 = (unsigned short*)alloc(32768);
    unsigned short* BpW3 = (unsigned short*)alloc(32768);
    unsigned short* Bp2  = (unsigned short*)alloc(16384);
    unsigned short* BpE  = (unsigned short*)alloc(8192);
    float* aggx = (float*)alloc((size_t)N * 8 * 4);
    unsigned short* bufA = (unsigned short*)alloc((size_t)N * H * 2);
    unsigned short* bufB = (unsigned short*)alloc((size_t)N * H * 2);
    unsigned short* Pm   = (unsigned short*)alloc((size_t)N * H * 2);
    unsigned short* Qm   = (unsigned short*)alloc((size_t)N * H * 2);

    // graph build (CSC with eid+col)
    hipMemsetAsync(cnt, 0, (size_t)N * 4, stream);
    count_kernel<<<(E + 255) / 256, 256, 0, stream>>>(col, E, cnt);
    scan_sum_kernel<<<NB, 256, 0, stream>>>(cnt, N, bsum);
    scan_offsets_kernel<<<1, 64, 0, stream>>>(bsum, NB, boff, col_start, N);
    scan_write_kernel<<<NB, 256, 0, stream>>>(cnt, N, boff, col_start, cursor, dinv);
    scatter_kernel<<<(E + 255) / 256, 256, 0, stream>>>(row, col, E, cursor, csc_src, csc_ec);

    // weight prep
    weff_kernel<<<64, 256, 0, stream>>>(We2, Wc1, Weff);
    bc1p_kernel<<<1, 128, 0, stream>>>(bc1, be2, Wc1, bc1p);
    packg_kernel<<<8, 256, 0, stream>>>(Wc1, BpA);
    packg_kernel<<<8, 256, 0, stream>>>(Wc1 + 128 * 128, BpB);
    packg_kernel<<<8, 256, 0, stream>>>(Weff, BpU);
    packg_kernel<<<8, 256, 0, stream>>>(W2, BpW2);
    packg_kernel<<<8, 256, 0, stream>>>(W3, BpW3);
    pack2_kernel<<<4, 256, 0, stream>>>(Wc2, Bp2);
    packwe1_kernel<<<2, 256, 0, stream>>>(We1, be1, BpE);

    // GCN: aggregate-then-transform, dinv-prescaled bf16 features
    aggx_kernel<<<(N * 8 + 255) / 256, 256, 0, stream>>>(x, col_start, csc_src, dinv, aggx, N);
    xform8bf_kernel<<<(N * 64 + 255) / 256, 256, 0, stream>>>(aggx, W1, b1, dinv,
                                                              (unsigned int*)bufA, N);   // h1d
    agg128bf_kernel<<<(N + 3) / 4, 256, 0, stream>>>((const unsigned int*)bufA, col_start, csc_src,
                                                     dinv, (unsigned int*)bufB, N);      // agg2
    xform_mfma_kernel<<<(N + 63) / 64, 256, 0, stream>>>(bufB, BpW2, b2, dinv, bufA, N); // h2d
    agg128bf_kernel<<<(N + 3) / 4, 256, 0, stream>>>((const unsigned int*)bufA, col_start, csc_src,
                                                     dinv, (unsigned int*)bufB, N);      // agg3
    h3pq_kernel<<<(N + 63) / 64, 256, 0, stream>>>(bufB, BpW3, b3, BpA, BpB, bc1p, Pm, Qm, N);

    // fused all-MFMA classifier in CSC order
    classifier_mfma2<<<ntiles, 256, 0, stream>>>(
        csc_src, csc_ec, ea, BpE, Pm, Qm, BpU, Bp2, bc2, Wc3, bc3, out, E);
}

// Round 13
// 462.435 us; speedup vs baseline: 1.5238x; 1.0316x over previous
//
#include <hip/hip_runtime.h>
#include <math.h>

#define H 128
#define STC 152   // LDS stride (shorts) for bf16 A-tiles
#define SOT 136   // LDS stride (shorts) for staged bf16 output tiles
#define SPQ 136   // LDS stride (shorts) for bf16 Spq
#define Z2S 69    // LDS stride (floats) for z2

typedef __attribute__((ext_vector_type(8))) short short8;
typedef __attribute__((ext_vector_type(4))) float f32x4;

__device__ inline unsigned short f2bf(float f) {
    unsigned int u = __float_as_uint(f);
    return (unsigned short)((u + 0x7fffu + ((u >> 16) & 1u)) >> 16);
}
__device__ inline float bflo(unsigned int v) { return __uint_as_float(v << 16); }
__device__ inline float bfhi(unsigned int v) { return __uint_as_float(v & 0xffff0000u); }
__device__ inline float bf2f(unsigned short v) { return __uint_as_float(((unsigned int)v) << 16); }

__device__ inline void fma4(float4& acc, float a, const float4 w) {
    acc.x = fmaf(a, w.x, acc.x);
    acc.y = fmaf(a, w.y, acc.y);
    acc.z = fmaf(a, w.z, acc.z);
    acc.w = fmaf(a, w.w, acc.w);
}

// ---------------- graph build ----------------

__global__ void count_kernel(const int* __restrict__ col, int E, int* __restrict__ cnt) {
    int e = blockIdx.x * blockDim.x + threadIdx.x;
    if (e < E) atomicAdd(&cnt[col[e]], 1);
}

__global__ void scan_sum_kernel(const int* __restrict__ cnt, int N, int* __restrict__ bsum) {
    int b = blockIdx.x, t = threadIdx.x;
    int base = b * 1024 + t * 4;
    int s = 0;
#pragma unroll
    for (int g = 0; g < 4; ++g) {
        int i = base + g;
        if (i < N) s += cnt[i];
    }
    for (int off = 32; off >= 1; off >>= 1) s += __shfl_down(s, off, 64);
    __shared__ int ws[4];
    if ((t & 63) == 0) ws[t >> 6] = s;
    __syncthreads();
    if (t == 0) bsum[b] = ws[0] + ws[1] + ws[2] + ws[3];
}

__global__ void scan_offsets_kernel(const int* __restrict__ bsum, int nb,
                                    int* __restrict__ boff, int* __restrict__ col_start, int N) {
    int lane = threadIdx.x;
    int v = (lane < nb) ? bsum[lane] : 0;
    int incl = v;
    for (int off = 1; off < 64; off <<= 1) {
        int u = __shfl_up(incl, off, 64);
        if (lane >= off) incl += u;
    }
    if (lane < nb) boff[lane] = incl - v;
    if (lane == 63) col_start[N] = incl;
}

__global__ void scan_write_kernel(const int* __restrict__ cnt, int N, const int* __restrict__ boff,
                                  int* __restrict__ col_start, int* __restrict__ cursor,
                                  float* __restrict__ dinv) {
    int b = blockIdx.x, t = threadIdx.x;
    int lane = t & 63, wv = t >> 6;
    int base = b * 1024 + t * 4;
    int c[4];
    int s = 0;
#pragma unroll
    for (int g = 0; g < 4; ++g) {
        int i = base + g;
        c[g] = (i < N) ? cnt[i] : 0;
        s += c[g];
    }
    int incl = s;
    for (int off = 1; off < 64; off <<= 1) {
        int u = __shfl_up(incl, off, 64);
        if (lane >= off) incl += u;
    }
    __shared__ int ws[4];
    if (lane == 63) ws[wv] = incl;
    __syncthreads();
    int run = boff[b] + incl - s;
    for (int w = 0; w < wv; ++w) run += ws[w];
#pragma unroll
    for (int g = 0; g < 4; ++g) {
        int i = base + g;
        if (i < N) {
            col_start[i] = run;
            cursor[i] = run;
            dinv[i] = rsqrtf((float)(c[g] + 1));
            run += c[g];
        }
    }
}

__global__ void scatter_kernel(const int* __restrict__ row, const int* __restrict__ col, int E,
                               int* __restrict__ cursor, int* __restrict__ csc_src,
                               int2* __restrict__ csc_ec) {
    int e = blockIdx.x * blockDim.x + threadIdx.x;
    if (e < E) {
        int c = col[e];
        int p = atomicAdd(&cursor[c], 1);
        csc_src[p] = row[e];
        csc_ec[p] = make_int2(e, c);
    }
}

// ---------------- GCN: aggregate-then-transform (bf16 dinv-prescaled features) ----------------

// wave-per-node aggregation on raw x: lane = (neighbor-slot j = lane>>3, feature f = lane&7)
// -> 8 neighbors in flight per wave instead of 1 per thread.
__global__ __launch_bounds__(256) void aggx_kernel(
    const float* __restrict__ x, const int* __restrict__ col_start,
    const int* __restrict__ csc_src, const float* __restrict__ dinv,
    float* __restrict__ aggx, int N) {
    int wv = threadIdx.x >> 6, lane = threadIdx.x & 63;
    int i = blockIdx.x * 4 + wv;
    if (i >= N) return;
    int f = lane & 7, j = lane >> 3;
    int s0 = col_start[i], s1 = col_start[i + 1];
    float acc = 0.f;
    int p = s0 + j;
    // 2-deep unroll: 16 neighbor rows in flight per wave
    for (; p + 8 < s1; p += 16) {
        int sa = csc_src[p], sb = csc_src[p + 8];
        float va = dinv[sa] * x[sa * 8 + f];
        float vb = dinv[sb] * x[sb * 8 + f];
        acc += va + vb;
    }
    if (p < s1) {
        int s = csc_src[p];
        acc = fmaf(dinv[s], x[s * 8 + f], acc);
    }
    acc += __shfl_xor(acc, 8, 64);
    acc += __shfl_xor(acc, 16, 64);
    acc += __shfl_xor(acc, 32, 64);
    if (j == 0) {
        float di = dinv[i];
        aggx[i * 8 + f] = fmaf(di, acc, di * di * x[i * 8 + f]);
    }
}

__global__ void xform8bf_kernel(const float* __restrict__ aggx, const float* __restrict__ W,
                                const float* __restrict__ b, const float* __restrict__ dinv,
                                unsigned int* __restrict__ out, int N) {
    int t = blockIdx.x * 256 + threadIdx.x;
    int i = t >> 6, jp = t & 63;
    if (i >= N) return;
    const float* ar = aggx + i * 8;
    float sc = dinv[i];
    int j0 = jp * 2;
    float a0 = b[j0], a1 = b[j0 + 1];
#pragma unroll
    for (int k = 0; k < 8; ++k) {
        float av = ar[k];
        a0 = fmaf(av, W[k * 128 + j0], a0);
        a1 = fmaf(av, W[k * 128 + j0 + 1], a1);
    }
    out[(size_t)i * 64 + jp] = (unsigned int)f2bf(sc * fmaxf(a0, 0.f)) |
                               ((unsigned int)f2bf(sc * fmaxf(a1, 0.f)) << 16);
}

// wave-per-node row-sum of prescaled bf16 rows; 16 row loads issued per batch
__global__ __launch_bounds__(256) void agg128bf_kernel(
    const unsigned int* __restrict__ hd, const int* __restrict__ col_start,
    const int* __restrict__ csc_src, const float* __restrict__ dinv,
    unsigned int* __restrict__ out, int N) {
    int wv = threadIdx.x >> 6, lane = threadIdx.x & 63;
    int i = blockIdx.x * 4 + wv;
    if (i >= N) return;
    int s0 = col_start[i], s1 = col_start[i + 1];
    float ax = 0.f, ay = 0.f;
    int p = s0;
    for (; p + 16 <= s1; p += 16) {
        unsigned int v[16];
#pragma unroll
        for (int k = 0; k < 16; ++k)
            v[k] = hd[(size_t)csc_src[p + k] * 64 + lane];
#pragma unroll
        for (int k = 0; k < 16; ++k) { ax += bflo(v[k]); ay += bfhi(v[k]); }
    }
    for (; p + 4 <= s1; p += 4) {
        unsigned int v0 = hd[(size_t)csc_src[p + 0] * 64 + lane];
        unsigned int v1 = hd[(size_t)csc_src[p + 1] * 64 + lane];
        unsigned int v2 = hd[(size_t)csc_src[p + 2] * 64 + lane];
        unsigned int v3 = hd[(size_t)csc_src[p + 3] * 64 + lane];
        ax += bflo(v0) + bflo(v1) + bflo(v2) + bflo(v3);
        ay += bfhi(v0) + bfhi(v1) + bfhi(v2) + bfhi(v3);
    }
    for (; p < s1; ++p) {
        unsigned int v = hd[(size_t)csc_src[p] * 64 + lane];
        ax += bflo(v); ay += bfhi(v);
    }
    float di = dinv[i];
    unsigned int vs = hd[(size_t)i * 64 + lane];
    float rx = di * (ax + bflo(vs));
    float ry = di * (ay + bfhi(vs));
    out[(size_t)i * 64 + lane] = (unsigned int)f2bf(rx) | ((unsigned int)f2bf(ry) << 16);
}

__global__ __launch_bounds__(256) void xform_mfma_kernel(
    const unsigned short* __restrict__ in, const unsigned short* __restrict__ Bp,
    const float* __restrict__ b, const float* __restrict__ scale,
    unsigned short* __restrict__ out, int N) {
    __shared__ __align__(16) unsigned short sm[64 * STC];
    int tid = threadIdx.x;
    int i0 = blockIdx.x * 64;
    for (int u = tid; u < 1024; u += 256) {
        int i = u >> 4, l = u & 15;
        int node = i0 + i; if (node >= N) node = N - 1;
        uint4 v = ((const uint4*)in)[(size_t)node * 16 + l];
        *(uint4*)&sm[i * STC + l * 8] = v;
    }
    __syncthreads();
    int lane = tid & 63, w = tid >> 6, lm = lane & 15, quad = lane >> 4;
    int nt0 = 2 * w, nt1 = 2 * w + 1;
    f32x4 acc0[4], acc1[4];
    {
        float bv0 = b[nt0 * 16 + lm], bv1 = b[nt1 * 16 + lm];
        for (int m = 0; m < 4; ++m)
            for (int r = 0; r < 4; ++r) { acc0[m][r] = bv0; acc1[m][r] = bv1; }
    }
#pragma unroll
    for (int s = 0; s < 4; ++s) {
        short8 b0 = *(const short8*)&Bp[((size_t)(s * 8 + nt0) * 64 + lane) * 8];
        short8 b1 = *(const short8*)&Bp[((size_t)(s * 8 + nt1) * 64 + lane) * 8];
#pragma unroll
        for (int m = 0; m < 4; ++m) {
            short8 afr = *(const short8*)&sm[(m * 16 + lm) * STC + s * 32 + quad * 8];
            acc0[m] = __builtin_amdgcn_mfma_f32_16x16x32_bf16(afr, b0, acc0[m], 0, 0, 0);
            acc1[m] = __builtin_amdgcn_mfma_f32_16x16x32_bf16(afr, b1, acc1[m], 0, 0, 0);
        }
    }
    __syncthreads();
    for (int m = 0; m < 4; ++m)
        for (int r = 0; r < 4; ++r) {
            int rw = m * 16 + quad * 4 + r;
            int node = i0 + rw; if (node >= N) node = N - 1;
            float sc = scale ? scale[node] : 1.f;
            sm[rw * SOT + nt0 * 16 + lm] = f2bf(sc * fmaxf(acc0[m][r], 0.f));
            sm[rw * SOT + nt1 * 16 + lm] = f2bf(sc * fmaxf(acc1[m][r], 0.f));
        }
    __syncthreads();
    for (int u = tid; u < 1024; u += 256) {
        int i = u >> 4, l = u & 15;
        int node = i0 + i;
        if (node < N)
            *(uint4*)&out[(size_t)node * 128 + l * 8] = *(uint4*)&sm[i * SOT + l * 8];
    }
}

// ---------------- classifier weight prep ----------------

__global__ void weff_kernel(const float* __restrict__ We2, const float* __restrict__ Wc1,
                            float* __restrict__ Weff) {
    int idx = blockIdx.x * blockDim.x + threadIdx.x;
    int k = idx >> 7, c = idx & 127;
    float acc = 0.f;
    for (int j = 0; j < 128; ++j)
        acc = fmaf(We2[k * 128 + j], Wc1[(256 + j) * 128 + c], acc);
    Weff[idx] = acc;
}

__global__ void bc1p_kernel(const float* __restrict__ bc1, const float* __restrict__ be2,
                            const float* __restrict__ Wc1, float* __restrict__ bc1p) {
    int c = threadIdx.x;
    float acc = bc1[c];
    for (int j = 0; j < 128; ++j)
        acc = fmaf(be2[j], Wc1[(256 + j) * 128 + c], acc);
    bc1p[c] = acc;
}

__global__ void packg_kernel(const float* __restrict__ src, unsigned short* __restrict__ dst) {
    int idx = blockIdx.x * 256 + threadIdx.x;  // 2048
    int s = idx >> 9, nt = (idx >> 6) & 7, lane = idx & 63;
    int quad = lane >> 4, lm = lane & 15;
    int n = nt * 16 + lm, k0 = s * 32 + quad * 8;
    unsigned int p[4];
#pragma unroll
    for (int g = 0; g < 4; ++g) {
        p[g] = (unsigned int)f2bf(src[(k0 + 2 * g) * 128 + n]) |
               ((unsigned int)f2bf(src[(k0 + 2 * g + 1) * 128 + n]) << 16);
    }
    *(uint4*)&dst[(size_t)idx * 8] = make_uint4(p[0], p[1], p[2], p[3]);
}

__global__ void pack2_kernel(const float* __restrict__ Wc2, unsigned short* __restrict__ Bp2) {
    int idx = blockIdx.x * 256 + threadIdx.x;  // 1024
    int s = idx >> 8, nt = (idx >> 6) & 3, lane = idx & 63;
    int quad = lane >> 4, lm = lane & 15;
    int n = nt * 16 + lm, k0 = s * 32 + quad * 8;
    unsigned int p[4];
#pragma unroll
    for (int g = 0; g < 4; ++g) {
        p[g] = (unsigned int)f2bf(Wc2[(k0 + 2 * g) * 64 + n]) |
               ((unsigned int)f2bf(Wc2[(k0 + 2 * g + 1) * 64 + n]) << 16);
    }
    *(uint4*)&Bp2[(size_t)idx * 8] = make_uint4(p[0], p[1], p[2], p[3]);
}

// pack We1_ext (rows 0..3 = We1, row 4 = be1, rows 5..31 = 0)
__global__ void packwe1_kernel(const float* __restrict__ We1, const float* __restrict__ be1,
                               unsigned short* __restrict__ BpE) {
    int idx = blockIdx.x * 256 + threadIdx.x;  // 512
    if (idx >= 512) return;
    int nt = idx >> 6, lane = idx & 63;
    int quad = lane >> 4, lm = lane & 15;
    int n = nt * 16 + lm, k0 = quad * 8;
    unsigned int p[4];
#pragma unroll
    for (int g = 0; g < 4; ++g) {
        int r0 = k0 + 2 * g, r1 = r0 + 1;
        float v0 = (r0 < 4) ? We1[r0 * 128 + n] : ((r0 == 4) ? be1[n] : 0.f);
        float v1 = (r1 < 4) ? We1[r1 * 128 + n] : ((r1 == 4) ? be1[n] : 0.f);
        p[g] = (unsigned int)f2bf(v0) | ((unsigned int)f2bf(v1) << 16);
    }
    *(uint4*)&BpE[(size_t)idx * 8] = make_uint4(p[0], p[1], p[2], p[3]);
}

// ---------------- fused h3 transform + P/Q precompute ----------------

__global__ __launch_bounds__(256) void h3pq_kernel(
    const unsigned short* __restrict__ in, const unsigned short* __restrict__ BpW3,
    const float* __restrict__ b3,
    const unsigned short* __restrict__ BpA, const unsigned short* __restrict__ BpB,
    const float* __restrict__ bc1p,
    unsigned short* __restrict__ P, unsigned short* __restrict__ Q, int N) {
    __shared__ __align__(16) unsigned short At[64 * STC];
    __shared__ __align__(16) unsigned short Hs[64 * SOT];
    int tid = threadIdx.x;
    int i0 = blockIdx.x * 64;
    for (int u = tid; u < 1024; u += 256) {
        int i = u >> 4, l = u & 15;
        int node = i0 + i; if (node >= N) node = N - 1;
        uint4 v = ((const uint4*)in)[(size_t)node * 16 + l];
        *(uint4*)&At[i * STC + l * 8] = v;
    }
    __syncthreads();
    int lane = tid & 63, w = tid >> 6, lm = lane & 15, quad = lane >> 4;

    {
        int nt0 = 2 * w, nt1 = 2 * w + 1;
        f32x4 a0[4], a1[4];
        float bv0 = b3[nt0 * 16 + lm], bv1 = b3[nt1 * 16 + lm];
        for (int m = 0; m < 4; ++m)
            for (int r = 0; r < 4; ++r) { a0[m][r] = bv0; a1[m][r] = bv1; }
#pragma unroll
        for (int s = 0; s < 4; ++s) {
            short8 b0 = *(const short8*)&BpW3[((size_t)(s * 8 + nt0) * 64 + lane) * 8];
            short8 b1 = *(const short8*)&BpW3[((size_t)(s * 8 + nt1) * 64 + lane) * 8];
#pragma unroll
            for (int m = 0; m < 4; ++m) {
                short8 afr = *(const short8*)&At[(m * 16 + lm) * STC + s * 32 + quad * 8];
                a0[m] = __builtin_amdgcn_mfma_f32_16x16x32_bf16(afr, b0, a0[m], 0, 0, 0);
                a1[m] = __builtin_amdgcn_mfma_f32_16x16x32_bf16(afr, b1, a1[m], 0, 0, 0);
            }
        }
        __syncthreads();
        for (int m = 0; m < 4; ++m)
            for (int r = 0; r < 4; ++r) {
                int rw = m * 16 + quad * 4 + r;
                Hs[rw * SOT + nt0 * 16 + lm] = f2bf(fmaxf(a0[m][r], 0.f));
                Hs[rw * SOT + nt1 * 16 + lm] = f2bf(fmaxf(a1[m][r], 0.f));
            }
    }
    __syncthreads();

    int half = w & 1;
    const unsigned short* Bp = (w >> 1) ? BpB : BpA;
    f32x4 acc[4][4];
    for (int nt = 0; nt < 4; ++nt) {
        float bv = (w >> 1) ? 0.f : bc1p[half * 64 + nt * 16 + lm];
        for (int m = 0; m < 4; ++m)
            for (int r = 0; r < 4; ++r) acc[nt][m][r] = bv;
    }
#pragma unroll
    for (int s = 0; s < 4; ++s) {
        short8 afr[4];
#pragma unroll
        for (int m = 0; m < 4; ++m)
            afr[m] = *(const short8*)&Hs[(m * 16 + lm) * SOT + s * 32 + quad * 8];
#pragma unroll
        for (int nt = 0; nt < 4; ++nt) {
            short8 bfr = *(const short8*)&Bp[((size_t)(s * 8 + half * 4 + nt) * 64 + lane) * 8];
#pragma unroll
            for (int m = 0; m < 4; ++m)
                acc[nt][m] = __builtin_amdgcn_mfma_f32_16x16x32_bf16(afr[m], bfr, acc[nt][m], 0, 0, 0);
        }
    }
    __syncthreads();
    unsigned short* St = At;

    if (w < 2) {
        for (int nt = 0; nt < 4; ++nt)
            for (int m = 0; m < 4; ++m)
                for (int r = 0; r < 4; ++r) {
                    int rw = m * 16 + quad * 4 + r;
                    St[rw * SOT + half * 64 + nt * 16 + lm] = f2bf(acc[nt][m][r]);
                }
    }
    __syncthreads();
    for (int u = tid; u < 1024; u += 256) {
        int i = u >> 4, l = u & 15;
        int node = i0 + i;
        if (node < N)
            *(uint4*)&P[(size_t)node * 128 + l * 8] = *(uint4*)&St[i * SOT + l * 8];
    }
    __syncthreads();
    if (w >= 2) {
        for (int nt = 0; nt < 4; ++nt)
            for (int m = 0; m < 4; ++m)
                for (int r = 0; r < 4; ++r) {
                    int rw = m * 16 + quad * 4 + r;
                    St[rw * SOT + half * 64 + nt * 16 + lm] = f2bf(acc[nt][m][r]);
                }
    }
    __syncthreads();
    for (int u = tid; u < 1024; u += 256) {
        int i = u >> 4, l = u & 15;
        int node = i0 + i;
        if (node < N)
            *(uint4*)&Q[(size_t)node * 128 + l * 8] = *(uint4*)&St[i * SOT + l * 8];
    }
}

// ---------------- fused classifier, all-MFMA (t-MLP via padded K=32 MFMA) ----------------

__global__ __launch_bounds__(256, 4) void classifier_mfma2(
    const int* __restrict__ csc_src, const int2* __restrict__ csc_ec,
    const float* __restrict__ ea, const unsigned short* __restrict__ BpE,
    const unsigned short* __restrict__ P, const unsigned short* __restrict__ Q,
    const unsigned short* __restrict__ BpU, const unsigned short* __restrict__ Bp2,
    const float* __restrict__ bc2, const float* __restrict__ Wc3, const float* __restrict__ bc3,
    float* __restrict__ out, int E) {
    __shared__ __align__(16) unsigned char smem[37888];
    unsigned short* SpqB = (unsigned short*)smem;         // [64][SPQ] bf16
    float* z2 = (float*)smem;                             // [64][Z2S] fp32 (overlay)
    unsigned short* At = (unsigned short*)(smem + 17664); // [64][STC] bf16 (t, then z1)
    unsigned short* z1 = At;                              // overlay
    float* part = (float*)(smem + 17664);                 // [4][64] (overlay)
    int* sS = (int*)(smem + 37120);
    int* eS = sS + 64;
    int* cS = eS + 64;

    int tid = threadIdx.x;
    int lane = tid & 63, w = tid >> 6, lm = lane & 15, quad = lane >> 4;
    int e0 = blockIdx.x * 64;

    short8 bE0 = *(const short8*)&BpE[((size_t)(2 * w) * 64 + lane) * 8];
    short8 bE1 = *(const short8*)&BpE[((size_t)(2 * w + 1) * 64 + lane) * 8];
    short8 b0s[4], b1s[4], b2s[4];
#pragma unroll
    for (int s = 0; s < 4; ++s) {
        b0s[s] = *(const short8*)&BpU[((size_t)(s * 8 + 2 * w) * 64 + lane) * 8];
        b1s[s] = *(const short8*)&BpU[((size_t)(s * 8 + 2 * w + 1) * 64 + lane) * 8];
        b2s[s] = *(const short8*)&Bp2[((size_t)(s * 4 + w) * 64 + lane) * 8];
    }
    float bv2 = bc2[w * 16 + lm];

    if (tid < 64) {
        int p = e0 + tid; if (p >= E) p = E - 1;
        sS[tid] = csc_src[p];
        int2 ec = csc_ec[p];
        eS[tid] = ec.x; cS[tid] = ec.y;
    }
    __syncthreads();

    {
        const uint4* P4 = (const uint4*)P;
        const uint4* Q4 = (const uint4*)Q;
        int l = tid & 15;
#pragma unroll
        for (int j = 0; j < 4; ++j) {
            int i = (tid >> 4) + 16 * j;
            uint4 pv = P4[(size_t)sS[i] * 16 + l];
            uint4 qv = Q4[(size_t)cS[i] * 16 + l];
            unsigned int o0 = (unsigned int)f2bf(bflo(pv.x) + bflo(qv.x)) |
                              ((unsigned int)f2bf(bfhi(pv.x) + bfhi(qv.x)) << 16);
            unsigned int o1 = (unsigned int)f2bf(bflo(pv.y) + bflo(qv.y)) |
                              ((unsigned int)f2bf(bfhi(pv.y) + bfhi(qv.y)) << 16);
            unsigned int o2 = (unsigned int)f2bf(bflo(pv.z) + bflo(qv.z)) |
                              ((unsigned int)f2bf(bfhi(pv.z) + bfhi(qv.z)) << 16);
            unsigned int o3 = (unsigned int)f2bf(bflo(pv.w) + bflo(qv.w)) |
                              ((unsigned int)f2bf(bfhi(pv.w) + bfhi(qv.w)) << 16);
            *(uint4*)&SpqB[i * SPQ + l * 8] = make_uint4(o0, o1, o2, o3);
        }
    }

    short8 eaf[4];
#pragma unroll
    for (int m = 0; m < 4; ++m) eaf[m] = (short8){0, 0, 0, 0, 0, 0, 0, 0};
    if (quad == 0) {
#pragma unroll
        for (int m = 0; m < 4; ++m) {
            int ed = eS[m * 16 + lm];
            float4 a = ((const float4*)ea)[ed];
            eaf[m][0] = (short)f2bf(a.x);
            eaf[m][1] = (short)f2bf(a.y);
            eaf[m][2] = (short)f2bf(a.z);
            eaf[m][3] = (short)f2bf(a.w);
            eaf[m][4] = (short)0x3F80;  // 1.0 bf16
        }
    }

    {
        f32x4 zacc = {0.f, 0.f, 0.f, 0.f};
#pragma unroll
        for (int m = 0; m < 4; ++m) {
            f32x4 t0 = __builtin_amdgcn_mfma_f32_16x16x32_bf16(eaf[m], bE0, zacc, 0, 0, 0);
            f32x4 t1 = __builtin_amdgcn_mfma_f32_16x16x32_bf16(eaf[m], bE1, zacc, 0, 0, 0);
#pragma unroll
            for (int r = 0; r < 4; ++r) {
                int rw = m * 16 + quad * 4 + r;
                At[rw * STC + 32 * w + lm]      = f2bf(fmaxf(t0[r], 0.f));
                At[rw * STC + 32 * w + 16 + lm] = f2bf(fmaxf(t1[r], 0.f));
            }
        }
    }
    __syncthreads();

    f32x4 acc0[4], acc1[4];
    for (int m = 0; m < 4; ++m)
        for (int r = 0; r < 4; ++r) { acc0[m][r] = 0.f; acc1[m][r] = 0.f; }
#pragma unroll
    for (int s = 0; s < 4; ++s) {
#pragma unroll
        for (int m = 0; m < 4; ++m) {
            short8 afr = *(const short8*)&At[(m * 16 + lm) * STC + s * 32 + quad * 8];
            acc0[m] = __builtin_amdgcn_mfma_f32_16x16x32_bf16(afr, b0s[s], acc0[m], 0, 0, 0);
            acc1[m] = __builtin_amdgcn_mfma_f32_16x16x32_bf16(afr, b1s[s], acc1[m], 0, 0, 0);
        }
    }
    for (int m = 0; m < 4; ++m)
        for (int r = 0; r < 4; ++r) {
            int rw = m * 16 + quad * 4 + r;
            acc0[m][r] = fmaxf(acc0[m][r] + bf2f(SpqB[rw * SPQ + 32 * w + lm]), 0.f);
            acc1[m][r] = fmaxf(acc1[m][r] + bf2f(SpqB[rw * SPQ + 32 * w + 16 + lm]), 0.f);
        }
    __syncthreads();
    for (int m = 0; m < 4; ++m)
        for (int r = 0; r < 4; ++r) {
            int rw = m * 16 + quad * 4 + r;
            z1[rw * STC + 32 * w + lm]      = f2bf(acc0[m][r]);
            z1[rw * STC + 32 * w + 16 + lm] = f2bf(acc1[m][r]);
        }
    __syncthreads();

    {
        f32x4 acc2[4];
        for (int m = 0; m < 4; ++m)
            for (int r = 0; r < 4; ++r) acc2[m][r] = bv2;
#pragma unroll
        for (int s = 0; s < 4; ++s) {
#pragma unroll
            for (int m = 0; m < 4; ++m) {
                short8 afr = *(const short8*)&z1[(m * 16 + lm) * STC + s * 32 + quad * 8];
                acc2[m] = __builtin_amdgcn_mfma_f32_16x16x32_bf16(afr, b2s[s], acc2[m], 0, 0, 0);
            }
        }
        for (int m = 0; m < 4; ++m)
            for (int r = 0; r < 4; ++r)
                z2[(m * 16 + quad * 4 + r) * Z2S + w * 16 + lm] = fmaxf(acc2[m][r], 0.f);
    }
    __syncthreads();

    {
        int e = tid & 63, q = tid >> 6;
        int c = q & 1, hf = q >> 1;
        const float* zr = z2 + e * Z2S + hf * 32;
        const float* wc = Wc3 + hf * 64 + c;
        float acc = 0.f;
#pragma unroll 8
        for (int kk = 0; kk < 32; ++kk)
            acc = fmaf(zr[kk], wc[2 * kk], acc);
        part[q * 64 + e] = acc;
    }
    __syncthreads();
    if (tid < 64) {
        int p = e0 + tid;
        if (p < E) {
            float l0 = bc3[0] + part[tid] + part[128 + tid];
            float l1 = bc3[1] + part[64 + tid] + part[192 + tid];
            float m = fmaxf(l0, l1);
            float lse = m + logf(expf(l0 - m) + expf(l1 - m));
            ((float2*)out)[eS[tid]] = make_float2(l0 - lse, l1 - lse);
        }
    }
}

// ---------------- launch ----------------

extern "C" void kernel_launch(void* const* d_in, const int* in_sizes, int n_in,
                              void* d_out, int out_size, void* d_ws, size_t ws_size,
                              hipStream_t stream) {
    const float* x   = (const float*)d_in[0];
    const int*   ei  = (const int*)d_in[1];
    const float* ea  = (const float*)d_in[2];
    const float* W1  = (const float*)d_in[3];
    const float* b1  = (const float*)d_in[4];
    const float* W2  = (const float*)d_in[5];
    const float* b2  = (const float*)d_in[6];
    const float* W3  = (const float*)d_in[7];
    const float* b3  = (const float*)d_in[8];
    const float* We1 = (const float*)d_in[9];
    const float* be1 = (const float*)d_in[10];
    const float* We2 = (const float*)d_in[11];
    const float* be2 = (const float*)d_in[12];
    const float* Wc1 = (const float*)d_in[13];
    const float* bc1 = (const float*)d_in[14];
    const float* Wc2 = (const float*)d_in[15];
    const float* bc2 = (const float*)d_in[16];
    const float* Wc3 = (const float*)d_in[17];
    const float* bc3 = (const float*)d_in[18];
    float* out = (float*)d_out;

    int N = in_sizes[0] / 8;
    int E = in_sizes[1] / 2;
    const int* row = ei;
    const int* col = ei + E;
    int NB = (N + 1023) / 1024;
    int ntiles = (E + 63) / 64;

    char* w = (char*)d_ws;
    auto alloc = [&](size_t bytes) { void* p = (void*)w; w += (bytes + 255) & ~(size_t)255; return p; };
    int*   cnt       = (int*)alloc((size_t)N * 4);
    int*   col_start = (int*)alloc((size_t)(N + 1) * 4);
    int*   cursor    = (int*)alloc((size_t)N * 4);
    int*   csc_src   = (int*)alloc((size_t)E * 4);
    int2*  csc_ec    = (int2*)alloc((size_t)E * 8);
    float* dinv      = (float*)alloc((size_t)N * 4);
    int*   bsum      = (int*)alloc(64 * 4);
    int*   boff      = (int*)alloc(64 * 4);
    float* Weff      = (float*)alloc(128 * 128 * 4);
    float* bc1p      = (float*)alloc(128 * 4);
    unsigned short* BpA  = (unsigned short*)alloc(32768);
    unsigned short* BpB  = (unsigned short*)alloc(32768);
    unsigned short* BpU  = (unsigned short*)alloc(32768);
    unsigned short* BpW2 = (unsigned short*)alloc(32768);
    unsigned short* BpW3 = (unsigned short*)alloc(32768);
    unsigned short* Bp2  = (unsigned short*)alloc(16384);
    unsigned short* BpE  = (unsigned short*)alloc(8192);
    float* aggx = (float*)alloc((size_t)N * 8 * 4);
    unsigned short* bufA = (unsigned short*)alloc((size_t)N * H * 2);
    unsigned short* bufB = (unsigned short*)alloc((size_t)N * H * 2);
    unsigned short* Pm   = (unsigned short*)alloc((size_t)N * H * 2);
    unsigned short* Qm   = (unsigned short*)alloc((size_t)N * H * 2);

    // graph build (CSC with eid+col)
    hipMemsetAsync(cnt, 0, (size_t)N * 4, stream);
    count_kernel<<<(E + 255) / 256, 256, 0, stream>>>(col, E, cnt);
    scan_sum_kernel<<<NB, 256, 0, stream>>>(cnt, N, bsum);
    scan_offsets_kernel<<<1, 64, 0, stream>>>(bsum, NB, boff, col_start, N);
    scan_write_kernel<<<NB, 256, 0, stream>>>(cnt, N, boff, col_start, cursor, dinv);
    scatter_kernel<<<(E + 255) / 256, 256, 0, stream>>>(row, col, E, cursor, csc_src, csc_ec);

    // weight prep
    weff_kernel<<<64, 256, 0, stream>>>(We2, Wc1, Weff);
    bc1p_kernel<<<1, 128, 0, stream>>>(bc1, be2, Wc1, bc1p);
    packg_kernel<<<8, 256, 0, stream>>>(Wc1, BpA);
    packg_kernel<<<8, 256, 0, stream>>>(Wc1 + 128 * 128, BpB);
    packg_kernel<<<8, 256, 0, stream>>>(Weff, BpU);
    packg_kernel<<<8, 256, 0, stream>>>(W2, BpW2);
    packg_kernel<<<8, 256, 0, stream>>>(W3, BpW3);
    pack2_kernel<<<4, 256, 0, stream>>>(Wc2, Bp2);
    packwe1_kernel<<<2, 256, 0, stream>>>(We1, be1, BpE);

    // GCN: aggregate-then-transform, dinv-prescaled bf16 features
    aggx_kernel<<<(N + 3) / 4, 256, 0, stream>>>(x, col_start, csc_src, dinv, aggx, N);
    xform8bf_kernel<<<(N * 64 + 255) / 256, 256, 0, stream>>>(aggx, W1, b1, dinv,
                                                              (unsigned int*)bufA, N);   // h1d
    agg128bf_kernel<<<(N + 3) / 4, 256, 0, stream>>>((const unsigned int*)bufA, col_start, csc_src,
                                                     dinv, (unsigned int*)bufB, N);      // agg2
    xform_mfma_kernel<<<(N + 63) / 64, 256, 0, stream>>>(bufB, BpW2, b2, dinv, bufA, N); // h2d
    agg128bf_kernel<<<(N + 3) / 4, 256, 0, stream>>>((const unsigned int*)bufA, col_start, csc_src,
                                                     dinv, (unsigned int*)bufB, N);      // agg3
    h3pq_kernel<<<(N + 63) / 64, 256, 0, stream>>>(bufB, BpW3, b3, BpA, BpB, bc1p, Pm, Qm, N);

    // fused all-MFMA classifier in CSC order
    classifier_mfma2<<<ntiles, 256, 0, stream>>>(
        csc_src, csc_ec, ea, BpE, Pm, Qm, BpU, Bp2, bc2, Wc3, bc3, out, E);
}